// Round 6
// baseline (757.352 us; speedup 1.0000x reference)
//
#include <hip/hip_runtime.h>
#include <cstdint>
#include <cmath>

typedef _Float16 half_t;
typedef _Float16 h2 __attribute__((ext_vector_type(2)));
typedef _Float16 h8 __attribute__((ext_vector_type(8)));
typedef float f4 __attribute__((ext_vector_type(4)));

// ---------------- CSR build ----------------

__global__ void count_kernel(const int* __restrict__ ei, int* __restrict__ counts, int E) {
    int e = blockIdx.x * blockDim.x + threadIdx.x;
    if (e < E) atomicAdd(&counts[ei[E + e]], 1);
}

#define SCAN_ELEMS 512

__global__ void partsum_kernel(const int* __restrict__ counts, int* __restrict__ bsums, int n) {
    __shared__ int sh[256];
    int b = blockIdx.x, t = threadIdx.x;
    int i0 = b * SCAN_ELEMS + t * 2;
    int s = 0;
    if (i0 < n) s += counts[i0];
    if (i0 + 1 < n) s += counts[i0 + 1];
    sh[t] = s;
    __syncthreads();
    for (int off = 128; off > 0; off >>= 1) {
        if (t < off) sh[t] += sh[t + off];
        __syncthreads();
    }
    if (t == 0) bsums[b] = sh[0];
}

__global__ void basescan_kernel(int* __restrict__ bsums, int* __restrict__ row_ptr,
                                int nb, int n) {
    __shared__ int sh[256];
    int t = threadIdx.x;
    int v = (t < nb) ? bsums[t] : 0;
    sh[t] = v;
    __syncthreads();
    for (int off = 1; off < 256; off <<= 1) {
        int u = (t >= off) ? sh[t - off] : 0;
        __syncthreads();
        sh[t] += u;
        __syncthreads();
    }
    if (t < nb) bsums[t] = sh[t] - v;
    if (t == 255) row_ptr[n] = sh[255];
}

__global__ void scanfill_kernel(const int* __restrict__ counts, const int* __restrict__ bsums,
                                int* __restrict__ row_ptr, int* __restrict__ woff,
                                float* __restrict__ dinv, int n) {
    __shared__ int sh[256];
    int b = blockIdx.x, t = threadIdx.x;
    int i0 = b * SCAN_ELEMS + 2 * t;
    int c0 = (i0 < n) ? counts[i0] : 0;
    int c1 = (i0 + 1 < n) ? counts[i0 + 1] : 0;
    int pair = c0 + c1;
    sh[t] = pair;
    __syncthreads();
    for (int off = 1; off < 256; off <<= 1) {
        int u = (t >= off) ? sh[t - off] : 0;
        __syncthreads();
        sh[t] += u;
        __syncthreads();
    }
    int base = bsums[b] + sh[t] - pair;
    if (i0 < n) {
        row_ptr[i0] = base;
        woff[i0] = base;
        dinv[i0] = rsqrtf((float)c0 + 1.0f);
    }
    if (i0 + 1 < n) {
        row_ptr[i0 + 1] = base + c0;
        woff[i0 + 1] = base + c0;
        dinv[i0 + 1] = rsqrtf((float)c1 + 1.0f);
    }
}

__global__ void fill_kernel(const int* __restrict__ ei, int* __restrict__ woff,
                            int* __restrict__ colidx, int E) {
    int e = blockIdx.x * blockDim.x + threadIdx.x;
    if (e < E) {
        int src = ei[e];
        int dst = ei[E + e];
        int pos = atomicAdd(&woff[dst], 1);
        colidx[pos] = src;
    }
}

// ---------------- conversions ----------------

__global__ void f2h_kernel(const float* __restrict__ x, half_t* __restrict__ xh, int total4) {
    int i = blockIdx.x * blockDim.x + threadIdx.x;
    if (i < total4) {
        float4 v = *(const float4*)&x[i * 4];
        half_t* p = xh + (size_t)i * 4;
        p[0] = (half_t)v.x; p[1] = (half_t)v.y; p[2] = (half_t)v.z; p[3] = (half_t)v.w;
    }
}

// Wt[n][k] = W[k][n], fp16, n zero-padded to Ncp
__global__ void wt_kernel(const float* __restrict__ W, half_t* __restrict__ Wt,
                          int K, int Nc, int Ncp) {
    int idx = blockIdx.x * blockDim.x + threadIdx.x;
    if (idx >= Ncp * K) return;
    int n = idx / K, k = idx - n * K;
    Wt[idx] = (n < Nc) ? (half_t)W[(size_t)k * Nc + n] : (half_t)0.f;
}

// ------- feature-sliced aggregation, XCD-pinned slices ----------------------------
// out[d,c] = dinv[d]*(sum_s dinv[s]*in[s,c] + dinv[d]*in[d,c])
// F = row width, S = F/32 slices. slice = blockIdx % S: with round-robin block->XCD
// dispatch each XCD touches only one slice (50000*32*2B = 3.2MB), L2-resident.
// 256 threads = 8 subwaves of 32 lanes; subwave = node, lane = column in slice.

template <int F, int S>
__global__ __launch_bounds__(256) void aggs_kernel(const half_t* __restrict__ in,
                                                   half_t* __restrict__ out,
                                                   const int* __restrict__ row_ptr,
                                                   const int* __restrict__ colidx,
                                                   const float* __restrict__ dinv, int n) {
    int bid = blockIdx.x;
    int slice = bid % S;
    int chunk = bid / S;
    int t = threadIdx.x;
    int node = chunk * 8 + (t >> 5);
    if (node >= n) return;
    int c = slice * 32 + (t & 31);
    float dv = dinv[node];
    float acc = dv * (float)in[(size_t)node * F + c];
    int beg = row_ptr[node], end = row_ptr[node + 1];
    for (int k = beg; k < end; ++k) {
        int s = colidx[k];
        acc = fmaf(dinv[s], (float)in[(size_t)s * F + c], acc);
    }
    out[(size_t)node * F + c] = (half_t)(dv * acc);
}

// final: z[N,64] fp16 (cols 40+ are zero) -> log_softmax over first 40 cols, f32 out
__global__ __launch_bounds__(256) void softmax40_kernel(const half_t* __restrict__ z,
                                                        const float* __restrict__ b4,
                                                        float* __restrict__ out, int n) {
    int node = blockIdx.x * 4 + (threadIdx.x >> 6);
    int c = threadIdx.x & 63;
    if (node >= n) return;
    float v = (c < 40) ? ((float)z[(size_t)node * 64 + c] + b4[c]) : -INFINITY;
    float m = v;
#pragma unroll
    for (int off = 32; off > 0; off >>= 1) m = fmaxf(m, __shfl_xor(m, off, 64));
    float e = (c < 40) ? expf(v - m) : 0.f;
    float s = e;
#pragma unroll
    for (int off = 32; off > 0; off >>= 1) s += __shfl_xor(s, off, 64);
    if (c < 40) out[(size_t)node * 40 + c] = v - m - logf(s);
}

// ---------------- MFMA GEMM ----------------

template <int K, int NT, bool FUSE>
__global__ __launch_bounds__(256) void mgemm_kernel(const half_t* __restrict__ A,
                                                    const half_t* __restrict__ Wt,  // [NT*16][K]
                                                    const float* __restrict__ AB,
                                                    const float* __restrict__ pa,
                                                    half_t* __restrict__ C,
                                                    int M, int Nc) {
    int wave = threadIdx.x >> 6;
    int lane = threadIdx.x & 63;
    int r0 = blockIdx.x * 64 + wave * 16;
    int arow = r0 + (lane & 15);
    int kgrp = lane >> 4;
    float alpha = FUSE ? pa[0] : 0.f;

    h8 af[K / 32];
    bool rowok = (arow < M);
    const half_t* Ap = A + (size_t)arow * K + kgrp * 8;
#pragma unroll
    for (int kk = 0; kk < K / 32; ++kk) {
        h8 v;
        if (rowok) {
            v = *(const h8*)(Ap + kk * 32);
        } else {
#pragma unroll
            for (int j = 0; j < 8; ++j) v[j] = (half_t)0.f;
        }
        if (FUSE) {
            int kb = kk * 32 + kgrp * 8;
#pragma unroll
            for (int j = 0; j < 8; ++j) {
                float u = (float)v[j] * AB[kb + j] + AB[256 + kb + j];
                u = (u >= 0.f) ? u : alpha * u;
                v[j] = (half_t)u;
            }
        }
        af[kk] = v;
    }

#pragma unroll 1
    for (int nt = 0; nt < NT; ++nt) {
        f4 acc = {0.f, 0.f, 0.f, 0.f};
        const half_t* Wp = Wt + (size_t)(nt * 16 + (lane & 15)) * K + kgrp * 8;
#pragma unroll
        for (int kk = 0; kk < K / 32; ++kk) {
            h8 bf = *(const h8*)(Wp + kk * 32);
            acc = __builtin_amdgcn_mfma_f32_16x16x32_f16(af[kk], bf, acc, 0, 0, 0);
        }
        int col = nt * 16 + (lane & 15);
        if (col < Nc) {
#pragma unroll
            for (int j = 0; j < 4; ++j) {
                int row = r0 + kgrp * 4 + j;
                if (row < M) C[(size_t)row * Nc + col] = (half_t)acc[j];
            }
        }
    }
}

// ---------------- BatchNorm stats ----------------

template <int F>
__global__ __launch_bounds__(256) void stats2_kernel(const half_t* __restrict__ z,
                                                     float* __restrict__ sums, int n) {
    constexpr int CB = F / 8;
    constexpr int RG = 256 / CB;
    __shared__ float red[256][16];
    int t = threadIdx.x;
    int cb = t % CB;
    int rg = t / CB;
    float sm[8], sq[8];
#pragma unroll
    for (int j = 0; j < 8; ++j) { sm[j] = 0.f; sq[j] = 0.f; }
    for (int r = blockIdx.x * RG + rg; r < n; r += gridDim.x * RG) {
        h8 v = *(const h8*)(z + (size_t)r * F + cb * 8);
#pragma unroll
        for (int j = 0; j < 8; ++j) {
            float f = (float)v[j];
            sm[j] += f;
            sq[j] = fmaf(f, f, sq[j]);
        }
    }
#pragma unroll
    for (int j = 0; j < 8; ++j) { red[t][j] = sm[j]; red[t][8 + j] = sq[j]; }
    __syncthreads();
    for (int o = t; o < 2 * F; o += 256) {
        int c = o % F, kind = o / F;
        int cbo = c >> 3, ci = (c & 7) + kind * 8;
        float v = 0.f;
#pragma unroll
        for (int g = 0; g < RG; ++g) v += red[g * CB + cbo][ci];
        atomicAdd(&sums[kind * 256 + c], v);
    }
}

__global__ void bnfin_kernel(const float* __restrict__ sums, const float* __restrict__ g,
                             const float* __restrict__ be, float* __restrict__ AB, int n, int F) {
    int c = threadIdx.x;
    if (c >= F) return;
    float mean = sums[c] / (float)n;
    float var = sums[256 + c] / (float)n - mean * mean;
    float rstd = rsqrtf(var + 1e-5f);
    float sc = g[c] * rstd;
    AB[c] = sc;
    AB[256 + c] = be[c] - mean * sc;
}

// ---------------- launch ----------------

extern "C" void kernel_launch(void* const* d_in, const int* in_sizes, int n_in,
                              void* d_out, int out_size, void* d_ws, size_t ws_size,
                              hipStream_t stream) {
    const float* x   = (const float*)d_in[0];
    const int*   ei  = (const int*)d_in[1];
    const float* W1  = (const float*)d_in[2];
    const float* g1  = (const float*)d_in[4];
    const float* be1 = (const float*)d_in[5];
    const float* W2  = (const float*)d_in[6];
    const float* g2  = (const float*)d_in[8];
    const float* be2 = (const float*)d_in[9];
    const float* W3  = (const float*)d_in[10];
    const float* g3  = (const float*)d_in[12];
    const float* be3 = (const float*)d_in[13];
    const float* W4  = (const float*)d_in[14];
    const float* b4  = (const float*)d_in[15];
    const float* pa  = (const float*)d_in[16];
    // b1,b2,b3 dropped: constants before BatchNorm cancel exactly in mean subtraction.

    int N = in_sizes[0] / 128;
    int E = in_sizes[1] / 2;

    char* ws = (char*)d_ws;
    size_t off = 0;
    auto carve = [&](size_t bytes) -> char* {
        char* p = ws + off;
        off += (bytes + 255) & ~(size_t)255;
        return p;
    };
    int nb = (N + SCAN_ELEMS - 1) / SCAN_ELEMS;
    float*  dinv    = (float*)carve((size_t)N * 4);
    int*    row_ptr = (int*)carve((size_t)(N + 1) * 4);
    int*    woff    = (int*)carve((size_t)N * 4);
    int*    counts  = (int*)carve((size_t)N * 4);
    int*    bsums   = (int*)carve((size_t)nb * 4);
    int*    colidx  = (int*)carve((size_t)E * 4);
    float*  stats   = (float*)carve(512 * 4);
    float*  bnAB    = (float*)carve(512 * 4);
    half_t* W1t     = (half_t*)carve((size_t)256 * 128 * 2);
    half_t* W2t     = (half_t*)carve((size_t)128 * 256 * 2);
    half_t* W3t     = (half_t*)carve((size_t)64 * 128 * 2);
    half_t* W4t     = (half_t*)carve((size_t)64 * 64 * 2);   // padded to 64 cols
    half_t* hA      = (half_t*)carve((size_t)N * 256 * 2);   // Z1
    half_t* hB      = (half_t*)carve((size_t)N * 128 * 2);   // xh, P2
    half_t* hC      = (half_t*)carve((size_t)N * 128 * 2);   // P1, Z2
    half_t* hD1     = (half_t*)carve((size_t)N * 64 * 2);    // P3, then Z4(agg out)
    half_t* hD2     = (half_t*)carve((size_t)N * 64 * 2);    // Z3
    half_t* hE64    = (half_t*)carve((size_t)N * 64 * 2);    // P4 padded [N,64]
    (void)n_in; (void)out_size; (void)ws_size;

    // CSR build
    hipMemsetAsync(counts, 0, (size_t)N * 4, stream);
    count_kernel<<<(E + 255) / 256, 256, 0, stream>>>(ei, counts, E);
    partsum_kernel<<<nb, 256, 0, stream>>>(counts, bsums, N);
    basescan_kernel<<<1, 256, 0, stream>>>(bsums, row_ptr, nb, N);
    scanfill_kernel<<<nb, 256, 0, stream>>>(counts, bsums, row_ptr, woff, dinv, N);
    fill_kernel<<<(E + 255) / 256, 256, 0, stream>>>(ei, woff, colidx, E);

    // weight convert+transpose (fp16)
    wt_kernel<<<(256 * 128 + 255) / 256, 256, 0, stream>>>(W1, W1t, 128, 256, 256);
    wt_kernel<<<(128 * 256 + 255) / 256, 256, 0, stream>>>(W2, W2t, 256, 128, 128);
    wt_kernel<<<(64 * 128 + 255) / 256, 256, 0, stream>>>(W3, W3t, 128, 64, 64);
    wt_kernel<<<(64 * 64 + 255) / 256, 256, 0, stream>>>(W4, W4t, 64, 40, 64);

    int gb = (N + 63) / 64;          // mgemm blocks
    int ac = (N + 7) / 8;            // agg node-chunks

    // L1: x->fp16, sliced agg(128), MFMA GEMM -> Z1 fp16 [N,256]
    f2h_kernel<<<(N * 128 / 4 + 255) / 256, 256, 0, stream>>>(x, hB, N * 128 / 4);
    aggs_kernel<128, 4><<<ac * 4, 256, 0, stream>>>(hB, hC, row_ptr, colidx, dinv, N);
    mgemm_kernel<128, 16, false><<<gb, 256, 0, stream>>>(hC, W1t, nullptr, nullptr, hA, N, 256);
    hipMemsetAsync(stats, 0, 512 * 4, stream);
    stats2_kernel<256><<<512, 256, 0, stream>>>(hA, stats, N);
    bnfin_kernel<<<1, 256, 0, stream>>>(stats, g1, be1, bnAB, N, 256);

    // L2: GEMM (BN1+PReLU fused) -> P2 fp16 [N,128], sliced agg -> Z2
    mgemm_kernel<256, 8, true><<<gb, 256, 0, stream>>>(hA, W2t, bnAB, pa, hB, N, 128);
    aggs_kernel<128, 4><<<ac * 4, 256, 0, stream>>>(hB, hC, row_ptr, colidx, dinv, N);
    hipMemsetAsync(stats, 0, 512 * 4, stream);
    stats2_kernel<128><<<512, 256, 0, stream>>>(hC, stats, N);
    bnfin_kernel<<<1, 256, 0, stream>>>(stats, g2, be2, bnAB, N, 128);

    // L3: GEMM (BN2 fused) -> P3 [N,64], sliced agg -> Z3
    mgemm_kernel<128, 4, true><<<gb, 256, 0, stream>>>(hC, W3t, bnAB, pa, hD1, N, 64);
    aggs_kernel<64, 2><<<ac * 2, 256, 0, stream>>>(hD1, hD2, row_ptr, colidx, dinv, N);
    hipMemsetAsync(stats, 0, 512 * 4, stream);
    stats2_kernel<64><<<512, 256, 0, stream>>>(hD2, stats, N);
    bnfin_kernel<<<1, 256, 0, stream>>>(stats, g3, be3, bnAB, N, 64);

    // L4: GEMM (BN3 fused) -> P4 padded [N,64] (cols 40+ = 0 via zero-padded W4t),
    //     sliced agg -> [N,64], softmax over first 40 cols (+b4) -> out f32
    mgemm_kernel<64, 4, true><<<gb, 256, 0, stream>>>(hD2, W4t, bnAB, pa, hE64, N, 64);
    aggs_kernel<64, 2><<<ac * 2, 256, 0, stream>>>(hE64, hD1, row_ptr, colidx, dinv, N);
    softmax40_kernel<<<(N + 3) / 4, 256, 0, stream>>>(hD1, b4, (float*)d_out, N);
}

// Round 7
// 420.172 us; speedup vs baseline: 1.8025x; 1.8025x over previous
//
#include <hip/hip_runtime.h>
#include <cstdint>
#include <cmath>

typedef _Float16 half_t;
typedef _Float16 h2 __attribute__((ext_vector_type(2)));
typedef _Float16 h8 __attribute__((ext_vector_type(8)));
typedef float f4 __attribute__((ext_vector_type(4)));

// ---------------- CSR build ----------------

__global__ void count_kernel(const int* __restrict__ ei, int* __restrict__ counts, int E) {
    int e = blockIdx.x * blockDim.x + threadIdx.x;
    if (e < E) atomicAdd(&counts[ei[E + e]], 1);
}

#define SCAN_ELEMS 512

__global__ void partsum_kernel(const int* __restrict__ counts, int* __restrict__ bsums, int n) {
    __shared__ int sh[256];
    int b = blockIdx.x, t = threadIdx.x;
    int i0 = b * SCAN_ELEMS + t * 2;
    int s = 0;
    if (i0 < n) s += counts[i0];
    if (i0 + 1 < n) s += counts[i0 + 1];
    sh[t] = s;
    __syncthreads();
    for (int off = 128; off > 0; off >>= 1) {
        if (t < off) sh[t] += sh[t + off];
        __syncthreads();
    }
    if (t == 0) bsums[b] = sh[0];
}

__global__ void basescan_kernel(int* __restrict__ bsums, int* __restrict__ row_ptr,
                                int nb, int n) {
    __shared__ int sh[256];
    int t = threadIdx.x;
    int v = (t < nb) ? bsums[t] : 0;
    sh[t] = v;
    __syncthreads();
    for (int off = 1; off < 256; off <<= 1) {
        int u = (t >= off) ? sh[t - off] : 0;
        __syncthreads();
        sh[t] += u;
        __syncthreads();
    }
    if (t < nb) bsums[t] = sh[t] - v;
    if (t == 255) row_ptr[n] = sh[255];
}

__global__ void scanfill_kernel(const int* __restrict__ counts, const int* __restrict__ bsums,
                                int* __restrict__ row_ptr, int* __restrict__ woff,
                                float* __restrict__ dinv, int n) {
    __shared__ int sh[256];
    int b = blockIdx.x, t = threadIdx.x;
    int i0 = b * SCAN_ELEMS + 2 * t;
    int c0 = (i0 < n) ? counts[i0] : 0;
    int c1 = (i0 + 1 < n) ? counts[i0 + 1] : 0;
    int pair = c0 + c1;
    sh[t] = pair;
    __syncthreads();
    for (int off = 1; off < 256; off <<= 1) {
        int u = (t >= off) ? sh[t - off] : 0;
        __syncthreads();
        sh[t] += u;
        __syncthreads();
    }
    int base = bsums[b] + sh[t] - pair;
    if (i0 < n) {
        row_ptr[i0] = base;
        woff[i0] = base;
        dinv[i0] = rsqrtf((float)c0 + 1.0f);
    }
    if (i0 + 1 < n) {
        row_ptr[i0 + 1] = base + c0;
        woff[i0 + 1] = base + c0;
        dinv[i0 + 1] = rsqrtf((float)c1 + 1.0f);
    }
}

__global__ void fill_kernel(const int* __restrict__ ei, int* __restrict__ woff,
                            int* __restrict__ colidx, int E) {
    int e = blockIdx.x * blockDim.x + threadIdx.x;
    if (e < E) {
        int src = ei[e];
        int dst = ei[E + e];
        int pos = atomicAdd(&woff[dst], 1);
        colidx[pos] = src;
    }
}

// ---------------- conversions ----------------

__global__ void f2h_kernel(const float* __restrict__ x, half_t* __restrict__ xh, int total4) {
    int i = blockIdx.x * blockDim.x + threadIdx.x;
    if (i < total4) {
        float4 v = *(const float4*)&x[i * 4];
        half_t* p = xh + (size_t)i * 4;
        p[0] = (half_t)v.x; p[1] = (half_t)v.y; p[2] = (half_t)v.z; p[3] = (half_t)v.w;
    }
}

// Wt[n][k] = W[k][n], fp16, n zero-padded to Ncp
__global__ void wt_kernel(const float* __restrict__ W, half_t* __restrict__ Wt,
                          int K, int Nc, int Ncp) {
    int idx = blockIdx.x * blockDim.x + threadIdx.x;
    if (idx >= Ncp * K) return;
    int n = idx / K, k = idx - n * K;
    Wt[idx] = (n < Nc) ? (half_t)W[(size_t)k * Nc + n] : (half_t)0.f;
}

// ------- aggregation (fp16): out[d] = dinv[d]*(sum dinv[s]*in[s] + dinv[d]*in[d]) --------
// One 64-lane wave per node, 4 nodes per 256-thread block.
// Edge loop unrolled x4: 4 independent colidx loads then 4 independent gathers
// per iteration -> ~4 outstanding misses per lane (latency-chain fix, G7).

__global__ __launch_bounds__(256) void aggh128_kernel(const half_t* __restrict__ in,
                                                      half_t* __restrict__ out,
                                                      const int* __restrict__ row_ptr,
                                                      const int* __restrict__ colidx,
                                                      const float* __restrict__ dinv, int n) {
    int node = blockIdx.x * 4 + (threadIdx.x >> 6);
    if (node >= n) return;
    int c = threadIdx.x & 63;  // h2 per lane
    float dv = dinv[node];
    h2 self = *(const h2*)(in + (size_t)node * 128 + 2 * c);
    float acc0 = dv * (float)self[0], acc1 = dv * (float)self[1];
    int beg = row_ptr[node], end = row_ptr[node + 1];
    int k = beg;
    for (; k + 3 < end; k += 4) {
        int s0 = colidx[k], s1 = colidx[k + 1], s2 = colidx[k + 2], s3 = colidx[k + 3];
        float d0 = dinv[s0], d1 = dinv[s1], d2 = dinv[s2], d3 = dinv[s3];
        h2 v0 = *(const h2*)(in + (size_t)s0 * 128 + 2 * c);
        h2 v1 = *(const h2*)(in + (size_t)s1 * 128 + 2 * c);
        h2 v2 = *(const h2*)(in + (size_t)s2 * 128 + 2 * c);
        h2 v3 = *(const h2*)(in + (size_t)s3 * 128 + 2 * c);
        acc0 = fmaf(d0, (float)v0[0], acc0); acc1 = fmaf(d0, (float)v0[1], acc1);
        acc0 = fmaf(d1, (float)v1[0], acc0); acc1 = fmaf(d1, (float)v1[1], acc1);
        acc0 = fmaf(d2, (float)v2[0], acc0); acc1 = fmaf(d2, (float)v2[1], acc1);
        acc0 = fmaf(d3, (float)v3[0], acc0); acc1 = fmaf(d3, (float)v3[1], acc1);
    }
    for (; k < end; ++k) {
        int s = colidx[k];
        float ds = dinv[s];
        h2 v = *(const h2*)(in + (size_t)s * 128 + 2 * c);
        acc0 = fmaf(ds, (float)v[0], acc0);
        acc1 = fmaf(ds, (float)v[1], acc1);
    }
    h2 r;
    r[0] = (half_t)(dv * acc0);
    r[1] = (half_t)(dv * acc1);
    *(h2*)(out + (size_t)node * 128 + 2 * c) = r;
}

__global__ __launch_bounds__(256) void aggh64_kernel(const half_t* __restrict__ in,
                                                     half_t* __restrict__ out,
                                                     const int* __restrict__ row_ptr,
                                                     const int* __restrict__ colidx,
                                                     const float* __restrict__ dinv, int n) {
    int node = blockIdx.x * 4 + (threadIdx.x >> 6);
    if (node >= n) return;
    int c = threadIdx.x & 63;
    float dv = dinv[node];
    float acc = dv * (float)in[(size_t)node * 64 + c];
    int beg = row_ptr[node], end = row_ptr[node + 1];
    int k = beg;
    for (; k + 3 < end; k += 4) {
        int s0 = colidx[k], s1 = colidx[k + 1], s2 = colidx[k + 2], s3 = colidx[k + 3];
        float d0 = dinv[s0], d1 = dinv[s1], d2 = dinv[s2], d3 = dinv[s3];
        float v0 = (float)in[(size_t)s0 * 64 + c];
        float v1 = (float)in[(size_t)s1 * 64 + c];
        float v2 = (float)in[(size_t)s2 * 64 + c];
        float v3 = (float)in[(size_t)s3 * 64 + c];
        acc = fmaf(d0, v0, acc);
        acc = fmaf(d1, v1, acc);
        acc = fmaf(d2, v2, acc);
        acc = fmaf(d3, v3, acc);
    }
    for (; k < end; ++k) {
        int s = colidx[k];
        acc = fmaf(dinv[s], (float)in[(size_t)s * 64 + c], acc);
    }
    out[(size_t)node * 64 + c] = (half_t)(dv * acc);
}

// final layer: aggregate (F=40) + b4 + log_softmax, one wave per node, 4 nodes/block
__global__ __launch_bounds__(256) void aggh_softmax_kernel(const half_t* __restrict__ in,
                                                           float* __restrict__ out,
                                                           const int* __restrict__ row_ptr,
                                                           const int* __restrict__ colidx,
                                                           const float* __restrict__ dinv,
                                                           const float* __restrict__ b4, int n) {
    int node = blockIdx.x * 4 + (threadIdx.x >> 6);
    if (node >= n) return;
    int c = threadIdx.x & 63;  // 40 active
    float dv = dinv[node];
    float acc = 0.f;
    if (c < 40) acc = dv * (float)in[(size_t)node * 40 + c];
    int beg = row_ptr[node], end = row_ptr[node + 1];
    int k = beg;
    for (; k + 3 < end; k += 4) {
        int s0 = colidx[k], s1 = colidx[k + 1], s2 = colidx[k + 2], s3 = colidx[k + 3];
        float d0 = dinv[s0], d1 = dinv[s1], d2 = dinv[s2], d3 = dinv[s3];
        if (c < 40) {
            float v0 = (float)in[(size_t)s0 * 40 + c];
            float v1 = (float)in[(size_t)s1 * 40 + c];
            float v2 = (float)in[(size_t)s2 * 40 + c];
            float v3 = (float)in[(size_t)s3 * 40 + c];
            acc = fmaf(d0, v0, acc);
            acc = fmaf(d1, v1, acc);
            acc = fmaf(d2, v2, acc);
            acc = fmaf(d3, v3, acc);
        }
    }
    for (; k < end; ++k) {
        int s = colidx[k];
        if (c < 40) acc = fmaf(dinv[s], (float)in[(size_t)s * 40 + c], acc);
    }
    float z = (c < 40) ? (dv * acc + b4[c]) : -INFINITY;
    float m = z;
#pragma unroll
    for (int off = 32; off > 0; off >>= 1) m = fmaxf(m, __shfl_xor(m, off, 64));
    float e = (c < 40) ? expf(z - m) : 0.f;
    float s = e;
#pragma unroll
    for (int off = 32; off > 0; off >>= 1) s += __shfl_xor(s, off, 64);
    if (c < 40) out[(size_t)node * 40 + c] = z - m - logf(s);
}

// ---------------- MFMA GEMM ----------------

template <int K, int NT, bool FUSE>
__global__ __launch_bounds__(256) void mgemm_kernel(const half_t* __restrict__ A,
                                                    const half_t* __restrict__ Wt,  // [NT*16][K]
                                                    const float* __restrict__ AB,
                                                    const float* __restrict__ pa,
                                                    half_t* __restrict__ C,
                                                    int M, int Nc) {
    int wave = threadIdx.x >> 6;
    int lane = threadIdx.x & 63;
    int r0 = blockIdx.x * 64 + wave * 16;
    int arow = r0 + (lane & 15);
    int kgrp = lane >> 4;
    float alpha = FUSE ? pa[0] : 0.f;

    h8 af[K / 32];
    bool rowok = (arow < M);
    const half_t* Ap = A + (size_t)arow * K + kgrp * 8;
#pragma unroll
    for (int kk = 0; kk < K / 32; ++kk) {
        h8 v;
        if (rowok) {
            v = *(const h8*)(Ap + kk * 32);
        } else {
#pragma unroll
            for (int j = 0; j < 8; ++j) v[j] = (half_t)0.f;
        }
        if (FUSE) {
            int kb = kk * 32 + kgrp * 8;
#pragma unroll
            for (int j = 0; j < 8; ++j) {
                float u = (float)v[j] * AB[kb + j] + AB[256 + kb + j];
                u = (u >= 0.f) ? u : alpha * u;
                v[j] = (half_t)u;
            }
        }
        af[kk] = v;
    }

#pragma unroll 1
    for (int nt = 0; nt < NT; ++nt) {
        f4 acc = {0.f, 0.f, 0.f, 0.f};
        const half_t* Wp = Wt + (size_t)(nt * 16 + (lane & 15)) * K + kgrp * 8;
#pragma unroll
        for (int kk = 0; kk < K / 32; ++kk) {
            h8 bf = *(const h8*)(Wp + kk * 32);
            acc = __builtin_amdgcn_mfma_f32_16x16x32_f16(af[kk], bf, acc, 0, 0, 0);
        }
        int col = nt * 16 + (lane & 15);
        if (col < Nc) {
#pragma unroll
            for (int j = 0; j < 4; ++j) {
                int row = r0 + kgrp * 4 + j;
                if (row < M) C[(size_t)row * Nc + col] = (half_t)acc[j];
            }
        }
    }
}

// ---------------- BatchNorm stats ----------------

template <int F>
__global__ __launch_bounds__(256) void stats2_kernel(const half_t* __restrict__ z,
                                                     float* __restrict__ sums, int n) {
    constexpr int CB = F / 8;
    constexpr int RG = 256 / CB;
    __shared__ float red[256][16];
    int t = threadIdx.x;
    int cb = t % CB;
    int rg = t / CB;
    float sm[8], sq[8];
#pragma unroll
    for (int j = 0; j < 8; ++j) { sm[j] = 0.f; sq[j] = 0.f; }
    for (int r = blockIdx.x * RG + rg; r < n; r += gridDim.x * RG) {
        h8 v = *(const h8*)(z + (size_t)r * F + cb * 8);
#pragma unroll
        for (int j = 0; j < 8; ++j) {
            float f = (float)v[j];
            sm[j] += f;
            sq[j] = fmaf(f, f, sq[j]);
        }
    }
#pragma unroll
    for (int j = 0; j < 8; ++j) { red[t][j] = sm[j]; red[t][8 + j] = sq[j]; }
    __syncthreads();
    for (int o = t; o < 2 * F; o += 256) {
        int c = o % F, kind = o / F;
        int cbo = c >> 3, ci = (c & 7) + kind * 8;
        float v = 0.f;
#pragma unroll
        for (int g = 0; g < RG; ++g) v += red[g * CB + cbo][ci];
        atomicAdd(&sums[kind * 256 + c], v);
    }
}

__global__ void bnfin_kernel(const float* __restrict__ sums, const float* __restrict__ g,
                             const float* __restrict__ be, float* __restrict__ AB, int n, int F) {
    int c = threadIdx.x;
    if (c >= F) return;
    float mean = sums[c] / (float)n;
    float var = sums[256 + c] / (float)n - mean * mean;
    float rstd = rsqrtf(var + 1e-5f);
    float sc = g[c] * rstd;
    AB[c] = sc;
    AB[256 + c] = be[c] - mean * sc;
}

// ---------------- launch ----------------

extern "C" void kernel_launch(void* const* d_in, const int* in_sizes, int n_in,
                              void* d_out, int out_size, void* d_ws, size_t ws_size,
                              hipStream_t stream) {
    const float* x   = (const float*)d_in[0];
    const int*   ei  = (const int*)d_in[1];
    const float* W1  = (const float*)d_in[2];
    const float* g1  = (const float*)d_in[4];
    const float* be1 = (const float*)d_in[5];
    const float* W2  = (const float*)d_in[6];
    const float* g2  = (const float*)d_in[8];
    const float* be2 = (const float*)d_in[9];
    const float* W3  = (const float*)d_in[10];
    const float* g3  = (const float*)d_in[12];
    const float* be3 = (const float*)d_in[13];
    const float* W4  = (const float*)d_in[14];
    const float* b4  = (const float*)d_in[15];
    const float* pa  = (const float*)d_in[16];
    // b1,b2,b3 dropped: constants before BatchNorm cancel exactly in mean subtraction.

    int N = in_sizes[0] / 128;
    int E = in_sizes[1] / 2;

    char* ws = (char*)d_ws;
    size_t off = 0;
    auto carve = [&](size_t bytes) -> char* {
        char* p = ws + off;
        off += (bytes + 255) & ~(size_t)255;
        return p;
    };
    int nb = (N + SCAN_ELEMS - 1) / SCAN_ELEMS;
    float*  dinv    = (float*)carve((size_t)N * 4);
    int*    row_ptr = (int*)carve((size_t)(N + 1) * 4);
    int*    woff    = (int*)carve((size_t)N * 4);
    int*    counts  = (int*)carve((size_t)N * 4);
    int*    bsums   = (int*)carve((size_t)nb * 4);
    int*    colidx  = (int*)carve((size_t)E * 4);
    float*  stats   = (float*)carve(512 * 4);
    float*  bnAB    = (float*)carve(512 * 4);
    half_t* W1t     = (half_t*)carve((size_t)256 * 128 * 2);
    half_t* W2t     = (half_t*)carve((size_t)128 * 256 * 2);
    half_t* W3t     = (half_t*)carve((size_t)64 * 128 * 2);
    half_t* W4t     = (half_t*)carve((size_t)48 * 64 * 2);  // padded to 48 cols
    half_t* hA      = (half_t*)carve((size_t)N * 256 * 2);  // Z1
    half_t* hB      = (half_t*)carve((size_t)N * 128 * 2);  // xh, P2
    half_t* hC      = (half_t*)carve((size_t)N * 128 * 2);  // P1, Z2
    half_t* hD1     = (half_t*)carve((size_t)N * 64 * 2);   // P3
    half_t* hD2     = (half_t*)carve((size_t)N * 64 * 2);   // Z3
    half_t* hE      = (half_t*)carve((size_t)N * 40 * 2);   // P4
    (void)n_in; (void)out_size; (void)ws_size;

    // CSR build
    hipMemsetAsync(counts, 0, (size_t)N * 4, stream);
    count_kernel<<<(E + 255) / 256, 256, 0, stream>>>(ei, counts, E);
    partsum_kernel<<<nb, 256, 0, stream>>>(counts, bsums, N);
    basescan_kernel<<<1, 256, 0, stream>>>(bsums, row_ptr, nb, N);
    scanfill_kernel<<<nb, 256, 0, stream>>>(counts, bsums, row_ptr, woff, dinv, N);
    fill_kernel<<<(E + 255) / 256, 256, 0, stream>>>(ei, woff, colidx, E);

    // weight convert+transpose (fp16)
    wt_kernel<<<(256 * 128 + 255) / 256, 256, 0, stream>>>(W1, W1t, 128, 256, 256);
    wt_kernel<<<(128 * 256 + 255) / 256, 256, 0, stream>>>(W2, W2t, 256, 128, 128);
    wt_kernel<<<(64 * 128 + 255) / 256, 256, 0, stream>>>(W3, W3t, 128, 64, 64);
    wt_kernel<<<(48 * 64 + 255) / 256, 256, 0, stream>>>(W4, W4t, 64, 40, 48);

    int gb = (N + 63) / 64;   // mgemm blocks
    int ab = (N + 3) / 4;     // agg blocks (4 nodes each)

    // L1: x->fp16, aggregate(128), MFMA GEMM -> Z1 fp16 [N,256]
    f2h_kernel<<<(N * 128 / 4 + 255) / 256, 256, 0, stream>>>(x, hB, N * 128 / 4);
    aggh128_kernel<<<ab, 256, 0, stream>>>(hB, hC, row_ptr, colidx, dinv, N);
    mgemm_kernel<128, 16, false><<<gb, 256, 0, stream>>>(hC, W1t, nullptr, nullptr, hA, N, 256);
    hipMemsetAsync(stats, 0, 512 * 4, stream);
    stats2_kernel<256><<<512, 256, 0, stream>>>(hA, stats, N);
    bnfin_kernel<<<1, 256, 0, stream>>>(stats, g1, be1, bnAB, N, 256);

    // L2: GEMM (BN1+PReLU fused) -> P2 fp16 [N,128], aggregate -> Z2
    mgemm_kernel<256, 8, true><<<gb, 256, 0, stream>>>(hA, W2t, bnAB, pa, hB, N, 128);
    aggh128_kernel<<<ab, 256, 0, stream>>>(hB, hC, row_ptr, colidx, dinv, N);
    hipMemsetAsync(stats, 0, 512 * 4, stream);
    stats2_kernel<128><<<512, 256, 0, stream>>>(hC, stats, N);
    bnfin_kernel<<<1, 256, 0, stream>>>(stats, g2, be2, bnAB, N, 128);

    // L3: GEMM (BN2 fused) -> P3 [N,64], aggregate -> Z3
    mgemm_kernel<128, 4, true><<<gb, 256, 0, stream>>>(hC, W3t, bnAB, pa, hD1, N, 64);
    aggh64_kernel<<<ab, 256, 0, stream>>>(hD1, hD2, row_ptr, colidx, dinv, N);
    hipMemsetAsync(stats, 0, 512 * 4, stream);
    stats2_kernel<64><<<512, 256, 0, stream>>>(hD2, stats, N);
    bnfin_kernel<<<1, 256, 0, stream>>>(stats, g3, be3, bnAB, N, 64);

    // L4: GEMM (BN3 fused) -> P4 [N,40], aggregate + b4 + log_softmax -> out (f32)
    mgemm_kernel<64, 3, true><<<gb, 256, 0, stream>>>(hD2, W4t, bnAB, pa, hE, N, 40);
    aggh_softmax_kernel<<<ab, 256, 0, stream>>>(hE, (float*)d_out, row_ptr, colidx, dinv, b4, N);
}

// Round 8
// 416.162 us; speedup vs baseline: 1.8198x; 1.0096x over previous
//
#include <hip/hip_runtime.h>
#include <cstdint>
#include <cmath>

typedef _Float16 half_t;
typedef _Float16 h2 __attribute__((ext_vector_type(2)));
typedef _Float16 h8 __attribute__((ext_vector_type(8)));
typedef float f4 __attribute__((ext_vector_type(4)));

// ================= CSR build: bucketed radix partition by dst>>8 =================
// Requires N <= 65536 (node ids packed in 16 bits). N=50000 here.
// Bucket = 256 consecutive dst nodes. Eliminates random global atomics and the
// 16x cross-XCD write amplification of scatter-fill (each colidx line is dirtied
// by exactly one block / one L2).

#define CSR_CHUNK 4096  // edges per block in hist/partition passes

// P1: per-(block,bucket) histogram. hcnt[bid*B + b]
__global__ __launch_bounds__(256) void csr_hist_kernel(const int* __restrict__ ei_dst,
                                                       int* __restrict__ hcnt,
                                                       int E, int B) {
    __shared__ int hist[256];
    int t = threadIdx.x;
    hist[t] = 0;
    __syncthreads();
    int base = blockIdx.x * CSR_CHUNK;
    int lim = min(base + CSR_CHUNK, E);
    for (int e = base + t; e < lim; e += 256) {
        int dst = ei_dst[e];
        atomicAdd(&hist[dst >> 8], 1);
    }
    __syncthreads();
    if (t < B) hcnt[blockIdx.x * B + t] = hist[t];
}

// P2: single block. Column-prefix hcnt in place (exclusive over blocks), bucket
// totals -> exclusive scan -> edge_base[b]; add base into columns. row_ptr[N]=E.
__global__ __launch_bounds__(256) void csr_scan_kernel(int* __restrict__ hcnt,
                                                       int* __restrict__ edge_base,
                                                       int* __restrict__ row_ptr,
                                                       int NB, int B, int E, int n) {
    __shared__ int sh[256];
    int t = threadIdx.x;
    int tot = 0;
    if (t < B) {
        for (int i = 0; i < NB; ++i) {
            int v = hcnt[i * B + t];
            hcnt[i * B + t] = tot;
            tot += v;
        }
    }
    sh[t] = (t < B) ? tot : 0;
    __syncthreads();
    for (int off = 1; off < 256; off <<= 1) {
        int u = (t >= off) ? sh[t - off] : 0;
        __syncthreads();
        sh[t] += u;
        __syncthreads();
    }
    int ebase = sh[t] - ((t < B) ? tot : 0);
    if (t < B) {
        edge_base[t] = ebase;
        for (int i = 0; i < NB; ++i) hcnt[i * B + t] += ebase;
    }
    if (t == 0) {
        edge_base[B] = E;
        row_ptr[n] = E;
    }
}

// P3: partition edges into bucket-contiguous ebuf, packed (dstl<<16)|src
__global__ __launch_bounds__(256) void csr_part_kernel(const int* __restrict__ ei,
                                                       const int* __restrict__ hcnt,
                                                       unsigned int* __restrict__ ebuf,
                                                       int E, int B) {
    __shared__ int lcur[256];
    int t = threadIdx.x;
    if (t < B) lcur[t] = hcnt[blockIdx.x * B + t];
    __syncthreads();
    int base = blockIdx.x * CSR_CHUNK;
    int lim = min(base + CSR_CHUNK, E);
    for (int e = base + t; e < lim; e += 256) {
        int src = ei[e];
        int dst = ei[E + e];
        int b = dst >> 8;
        int pos = atomicAdd(&lcur[b], 1);
        ebuf[pos] = ((unsigned int)(dst & 255) << 16) | (unsigned int)src;
    }
}

// P4: one block per bucket: LDS count -> scan -> row_ptr/dinv/fill (ushort colidx)
__global__ __launch_bounds__(256) void csr_fill_kernel(const unsigned int* __restrict__ ebuf,
                                                       const int* __restrict__ edge_base,
                                                       int* __restrict__ row_ptr,
                                                       float* __restrict__ dinv,
                                                       unsigned short* __restrict__ colidx,
                                                       int n) {
    __shared__ int cnt[256];
    __shared__ int sc[256];
    __shared__ int cur[256];
    int b = blockIdx.x;
    int t = threadIdx.x;
    int seg_beg = edge_base[b];
    int seg_end = edge_base[b + 1];
    cnt[t] = 0;
    __syncthreads();
    for (int e = seg_beg + t; e < seg_end; e += 256)
        atomicAdd(&cnt[ebuf[e] >> 16], 1);
    __syncthreads();
    sc[t] = cnt[t];
    __syncthreads();
    for (int off = 1; off < 256; off <<= 1) {
        int u = (t >= off) ? sc[t - off] : 0;
        __syncthreads();
        sc[t] += u;
        __syncthreads();
    }
    int excl = seg_beg + sc[t] - cnt[t];
    int node = (b << 8) + t;
    if (node < n) {
        row_ptr[node] = excl;
        dinv[node] = rsqrtf((float)cnt[t] + 1.0f);
    }
    cur[t] = excl;
    __syncthreads();
    for (int e = seg_beg + t; e < seg_end; e += 256) {
        unsigned int p = ebuf[e];
        int pos = atomicAdd(&cur[p >> 16], 1);
        colidx[pos] = (unsigned short)(p & 0xffff);
    }
}

// ---------------- conversions ----------------

__global__ void f2h_kernel(const float* __restrict__ x, half_t* __restrict__ xh, int total4) {
    int i = blockIdx.x * blockDim.x + threadIdx.x;
    if (i < total4) {
        float4 v = *(const float4*)&x[i * 4];
        half_t* p = xh + (size_t)i * 4;
        p[0] = (half_t)v.x; p[1] = (half_t)v.y; p[2] = (half_t)v.z; p[3] = (half_t)v.w;
    }
}

// Wt[n][k] = W[k][n], fp16, n zero-padded to Ncp
__global__ void wt_kernel(const float* __restrict__ W, half_t* __restrict__ Wt,
                          int K, int Nc, int Ncp) {
    int idx = blockIdx.x * blockDim.x + threadIdx.x;
    if (idx >= Ncp * K) return;
    int n = idx / K, k = idx - n * K;
    Wt[idx] = (n < Nc) ? (half_t)W[(size_t)k * Nc + n] : (half_t)0.f;
}

// ------- aggregation (fp16): out[d] = dinv[d]*(sum dinv[s]*in[s] + dinv[d]*in[d]) --------
// One 64-lane wave per node, 4 nodes per block; edge loop unrolled x4 for MLP (G7).

__global__ __launch_bounds__(256) void aggh128_kernel(const half_t* __restrict__ in,
                                                      half_t* __restrict__ out,
                                                      const int* __restrict__ row_ptr,
                                                      const unsigned short* __restrict__ colidx,
                                                      const float* __restrict__ dinv, int n) {
    int node = blockIdx.x * 4 + (threadIdx.x >> 6);
    if (node >= n) return;
    int c = threadIdx.x & 63;  // h2 per lane
    float dv = dinv[node];
    h2 self = *(const h2*)(in + (size_t)node * 128 + 2 * c);
    float acc0 = dv * (float)self[0], acc1 = dv * (float)self[1];
    int beg = row_ptr[node], end = row_ptr[node + 1];
    int k = beg;
    for (; k + 3 < end; k += 4) {
        int s0 = colidx[k], s1 = colidx[k + 1], s2 = colidx[k + 2], s3 = colidx[k + 3];
        float d0 = dinv[s0], d1 = dinv[s1], d2 = dinv[s2], d3 = dinv[s3];
        h2 v0 = *(const h2*)(in + (size_t)s0 * 128 + 2 * c);
        h2 v1 = *(const h2*)(in + (size_t)s1 * 128 + 2 * c);
        h2 v2 = *(const h2*)(in + (size_t)s2 * 128 + 2 * c);
        h2 v3 = *(const h2*)(in + (size_t)s3 * 128 + 2 * c);
        acc0 = fmaf(d0, (float)v0[0], acc0); acc1 = fmaf(d0, (float)v0[1], acc1);
        acc0 = fmaf(d1, (float)v1[0], acc0); acc1 = fmaf(d1, (float)v1[1], acc1);
        acc0 = fmaf(d2, (float)v2[0], acc0); acc1 = fmaf(d2, (float)v2[1], acc1);
        acc0 = fmaf(d3, (float)v3[0], acc0); acc1 = fmaf(d3, (float)v3[1], acc1);
    }
    for (; k < end; ++k) {
        int s = colidx[k];
        float ds = dinv[s];
        h2 v = *(const h2*)(in + (size_t)s * 128 + 2 * c);
        acc0 = fmaf(ds, (float)v[0], acc0);
        acc1 = fmaf(ds, (float)v[1], acc1);
    }
    h2 r;
    r[0] = (half_t)(dv * acc0);
    r[1] = (half_t)(dv * acc1);
    *(h2*)(out + (size_t)node * 128 + 2 * c) = r;
}

__global__ __launch_bounds__(256) void aggh64_kernel(const half_t* __restrict__ in,
                                                     half_t* __restrict__ out,
                                                     const int* __restrict__ row_ptr,
                                                     const unsigned short* __restrict__ colidx,
                                                     const float* __restrict__ dinv, int n) {
    int node = blockIdx.x * 4 + (threadIdx.x >> 6);
    if (node >= n) return;
    int c = threadIdx.x & 63;
    float dv = dinv[node];
    float acc = dv * (float)in[(size_t)node * 64 + c];
    int beg = row_ptr[node], end = row_ptr[node + 1];
    int k = beg;
    for (; k + 3 < end; k += 4) {
        int s0 = colidx[k], s1 = colidx[k + 1], s2 = colidx[k + 2], s3 = colidx[k + 3];
        float d0 = dinv[s0], d1 = dinv[s1], d2 = dinv[s2], d3 = dinv[s3];
        float v0 = (float)in[(size_t)s0 * 64 + c];
        float v1 = (float)in[(size_t)s1 * 64 + c];
        float v2 = (float)in[(size_t)s2 * 64 + c];
        float v3 = (float)in[(size_t)s3 * 64 + c];
        acc = fmaf(d0, v0, acc);
        acc = fmaf(d1, v1, acc);
        acc = fmaf(d2, v2, acc);
        acc = fmaf(d3, v3, acc);
    }
    for (; k < end; ++k) {
        int s = colidx[k];
        acc = fmaf(dinv[s], (float)in[(size_t)s * 64 + c], acc);
    }
    out[(size_t)node * 64 + c] = (half_t)(dv * acc);
}

// final layer: aggregate (F=40) + b4 + log_softmax, one wave per node, 4 nodes/block
__global__ __launch_bounds__(256) void aggh_softmax_kernel(const half_t* __restrict__ in,
                                                           float* __restrict__ out,
                                                           const int* __restrict__ row_ptr,
                                                           const unsigned short* __restrict__ colidx,
                                                           const float* __restrict__ dinv,
                                                           const float* __restrict__ b4, int n) {
    int node = blockIdx.x * 4 + (threadIdx.x >> 6);
    if (node >= n) return;
    int c = threadIdx.x & 63;  // 40 active
    float dv = dinv[node];
    float acc = 0.f;
    if (c < 40) acc = dv * (float)in[(size_t)node * 40 + c];
    int beg = row_ptr[node], end = row_ptr[node + 1];
    int k = beg;
    for (; k + 3 < end; k += 4) {
        int s0 = colidx[k], s1 = colidx[k + 1], s2 = colidx[k + 2], s3 = colidx[k + 3];
        float d0 = dinv[s0], d1 = dinv[s1], d2 = dinv[s2], d3 = dinv[s3];
        if (c < 40) {
            float v0 = (float)in[(size_t)s0 * 40 + c];
            float v1 = (float)in[(size_t)s1 * 40 + c];
            float v2 = (float)in[(size_t)s2 * 40 + c];
            float v3 = (float)in[(size_t)s3 * 40 + c];
            acc = fmaf(d0, v0, acc);
            acc = fmaf(d1, v1, acc);
            acc = fmaf(d2, v2, acc);
            acc = fmaf(d3, v3, acc);
        }
    }
    for (; k < end; ++k) {
        int s = colidx[k];
        if (c < 40) acc = fmaf(dinv[s], (float)in[(size_t)s * 40 + c], acc);
    }
    float z = (c < 40) ? (dv * acc + b4[c]) : -INFINITY;
    float m = z;
#pragma unroll
    for (int off = 32; off > 0; off >>= 1) m = fmaxf(m, __shfl_xor(m, off, 64));
    float e = (c < 40) ? expf(z - m) : 0.f;
    float s = e;
#pragma unroll
    for (int off = 32; off > 0; off >>= 1) s += __shfl_xor(s, off, 64);
    if (c < 40) out[(size_t)node * 40 + c] = z - m - logf(s);
}

// ---------------- MFMA GEMM ----------------

template <int K, int NT, bool FUSE>
__global__ __launch_bounds__(256) void mgemm_kernel(const half_t* __restrict__ A,
                                                    const half_t* __restrict__ Wt,  // [NT*16][K]
                                                    const float* __restrict__ AB,
                                                    const float* __restrict__ pa,
                                                    half_t* __restrict__ C,
                                                    int M, int Nc) {
    int wave = threadIdx.x >> 6;
    int lane = threadIdx.x & 63;
    int r0 = blockIdx.x * 64 + wave * 16;
    int arow = r0 + (lane & 15);
    int kgrp = lane >> 4;
    float alpha = FUSE ? pa[0] : 0.f;

    h8 af[K / 32];
    bool rowok = (arow < M);
    const half_t* Ap = A + (size_t)arow * K + kgrp * 8;
#pragma unroll
    for (int kk = 0; kk < K / 32; ++kk) {
        h8 v;
        if (rowok) {
            v = *(const h8*)(Ap + kk * 32);
        } else {
#pragma unroll
            for (int j = 0; j < 8; ++j) v[j] = (half_t)0.f;
        }
        if (FUSE) {
            int kb = kk * 32 + kgrp * 8;
#pragma unroll
            for (int j = 0; j < 8; ++j) {
                float u = (float)v[j] * AB[kb + j] + AB[256 + kb + j];
                u = (u >= 0.f) ? u : alpha * u;
                v[j] = (half_t)u;
            }
        }
        af[kk] = v;
    }

#pragma unroll 1
    for (int nt = 0; nt < NT; ++nt) {
        f4 acc = {0.f, 0.f, 0.f, 0.f};
        const half_t* Wp = Wt + (size_t)(nt * 16 + (lane & 15)) * K + kgrp * 8;
#pragma unroll
        for (int kk = 0; kk < K / 32; ++kk) {
            h8 bf = *(const h8*)(Wp + kk * 32);
            acc = __builtin_amdgcn_mfma_f32_16x16x32_f16(af[kk], bf, acc, 0, 0, 0);
        }
        int col = nt * 16 + (lane & 15);
        if (col < Nc) {
#pragma unroll
            for (int j = 0; j < 4; ++j) {
                int row = r0 + kgrp * 4 + j;
                if (row < M) C[(size_t)row * Nc + col] = (half_t)acc[j];
            }
        }
    }
}

// ---------------- BatchNorm stats ----------------

template <int F>
__global__ __launch_bounds__(256) void stats2_kernel(const half_t* __restrict__ z,
                                                     float* __restrict__ sums, int n) {
    constexpr int CB = F / 8;
    constexpr int RG = 256 / CB;
    __shared__ float red[256][16];
    int t = threadIdx.x;
    int cb = t % CB;
    int rg = t / CB;
    float sm[8], sq[8];
#pragma unroll
    for (int j = 0; j < 8; ++j) { sm[j] = 0.f; sq[j] = 0.f; }
    for (int r = blockIdx.x * RG + rg; r < n; r += gridDim.x * RG) {
        h8 v = *(const h8*)(z + (size_t)r * F + cb * 8);
#pragma unroll
        for (int j = 0; j < 8; ++j) {
            float f = (float)v[j];
            sm[j] += f;
            sq[j] = fmaf(f, f, sq[j]);
        }
    }
#pragma unroll
    for (int j = 0; j < 8; ++j) { red[t][j] = sm[j]; red[t][8 + j] = sq[j]; }
    __syncthreads();
    for (int o = t; o < 2 * F; o += 256) {
        int c = o % F, kind = o / F;
        int cbo = c >> 3, ci = (c & 7) + kind * 8;
        float v = 0.f;
#pragma unroll
        for (int g = 0; g < RG; ++g) v += red[g * CB + cbo][ci];
        atomicAdd(&sums[kind * 256 + c], v);
    }
}

__global__ void bnfin_kernel(const float* __restrict__ sums, const float* __restrict__ g,
                             const float* __restrict__ be, float* __restrict__ AB, int n, int F) {
    int c = threadIdx.x;
    if (c >= F) return;
    float mean = sums[c] / (float)n;
    float var = sums[256 + c] / (float)n - mean * mean;
    float rstd = rsqrtf(var + 1e-5f);
    float sc = g[c] * rstd;
    AB[c] = sc;
    AB[256 + c] = be[c] - mean * sc;
}

// ---------------- launch ----------------

extern "C" void kernel_launch(void* const* d_in, const int* in_sizes, int n_in,
                              void* d_out, int out_size, void* d_ws, size_t ws_size,
                              hipStream_t stream) {
    const float* x   = (const float*)d_in[0];
    const int*   ei  = (const int*)d_in[1];
    const float* W1  = (const float*)d_in[2];
    const float* g1  = (const float*)d_in[4];
    const float* be1 = (const float*)d_in[5];
    const float* W2  = (const float*)d_in[6];
    const float* g2  = (const float*)d_in[8];
    const float* be2 = (const float*)d_in[9];
    const float* W3  = (const float*)d_in[10];
    const float* g3  = (const float*)d_in[12];
    const float* be3 = (const float*)d_in[13];
    const float* W4  = (const float*)d_in[14];
    const float* b4  = (const float*)d_in[15];
    const float* pa  = (const float*)d_in[16];
    // b1,b2,b3 dropped: constants before BatchNorm cancel exactly in mean subtraction.

    int N = in_sizes[0] / 128;
    int E = in_sizes[1] / 2;
    int B = (N + 255) >> 8;                      // dst buckets (<=256 since N<=65536)
    int NB = (E + CSR_CHUNK - 1) / CSR_CHUNK;    // hist/partition blocks

    char* ws = (char*)d_ws;
    size_t off = 0;
    auto carve = [&](size_t bytes) -> char* {
        char* p = ws + off;
        off += (bytes + 255) & ~(size_t)255;
        return p;
    };
    float*          dinv      = (float*)carve((size_t)N * 4);
    int*            row_ptr   = (int*)carve((size_t)(N + 1) * 4);
    int*            hcnt      = (int*)carve((size_t)NB * B * 4);
    int*            edge_base = (int*)carve((size_t)(B + 1) * 4);
    unsigned int*   ebuf      = (unsigned int*)carve((size_t)E * 4);
    unsigned short* colidx    = (unsigned short*)carve((size_t)E * 2);
    float*          stats     = (float*)carve(512 * 4);
    float*          bnAB      = (float*)carve(512 * 4);
    half_t* W1t = (half_t*)carve((size_t)256 * 128 * 2);
    half_t* W2t = (half_t*)carve((size_t)128 * 256 * 2);
    half_t* W3t = (half_t*)carve((size_t)64 * 128 * 2);
    half_t* W4t = (half_t*)carve((size_t)48 * 64 * 2);  // padded to 48 cols
    half_t* hA  = (half_t*)carve((size_t)N * 256 * 2);  // Z1
    half_t* hB  = (half_t*)carve((size_t)N * 128 * 2);  // xh, P2
    half_t* hC  = (half_t*)carve((size_t)N * 128 * 2);  // P1, Z2
    half_t* hD1 = (half_t*)carve((size_t)N * 64 * 2);   // P3
    half_t* hD2 = (half_t*)carve((size_t)N * 64 * 2);   // Z3
    half_t* hE  = (half_t*)carve((size_t)N * 40 * 2);   // P4
    (void)n_in; (void)out_size; (void)ws_size;

    // CSR build (bucketed, no global atomics, single-owner colidx lines)
    csr_hist_kernel<<<NB, 256, 0, stream>>>(ei + E, hcnt, E, B);
    csr_scan_kernel<<<1, 256, 0, stream>>>(hcnt, edge_base, row_ptr, NB, B, E, N);
    csr_part_kernel<<<NB, 256, 0, stream>>>(ei, hcnt, ebuf, E, B);
    csr_fill_kernel<<<B, 256, 0, stream>>>(ebuf, edge_base, row_ptr, dinv, colidx, N);

    // weight convert+transpose (fp16)
    wt_kernel<<<(256 * 128 + 255) / 256, 256, 0, stream>>>(W1, W1t, 128, 256, 256);
    wt_kernel<<<(128 * 256 + 255) / 256, 256, 0, stream>>>(W2, W2t, 256, 128, 128);
    wt_kernel<<<(64 * 128 + 255) / 256, 256, 0, stream>>>(W3, W3t, 128, 64, 64);
    wt_kernel<<<(48 * 64 + 255) / 256, 256, 0, stream>>>(W4, W4t, 64, 40, 48);

    int gb = (N + 63) / 64;   // mgemm blocks
    int ab = (N + 3) / 4;     // agg blocks (4 nodes each)

    // L1: x->fp16, aggregate(128), MFMA GEMM -> Z1 fp16 [N,256]
    f2h_kernel<<<(N * 128 / 4 + 255) / 256, 256, 0, stream>>>(x, hB, N * 128 / 4);
    aggh128_kernel<<<ab, 256, 0, stream>>>(hB, hC, row_ptr, colidx, dinv, N);
    mgemm_kernel<128, 16, false><<<gb, 256, 0, stream>>>(hC, W1t, nullptr, nullptr, hA, N, 256);
    hipMemsetAsync(stats, 0, 512 * 4, stream);
    stats2_kernel<256><<<512, 256, 0, stream>>>(hA, stats, N);
    bnfin_kernel<<<1, 256, 0, stream>>>(stats, g1, be1, bnAB, N, 256);

    // L2: GEMM (BN1+PReLU fused) -> P2 fp16 [N,128], aggregate -> Z2
    mgemm_kernel<256, 8, true><<<gb, 256, 0, stream>>>(hA, W2t, bnAB, pa, hB, N, 128);
    aggh128_kernel<<<ab, 256, 0, stream>>>(hB, hC, row_ptr, colidx, dinv, N);
    hipMemsetAsync(stats, 0, 512 * 4, stream);
    stats2_kernel<128><<<512, 256, 0, stream>>>(hC, stats, N);
    bnfin_kernel<<<1, 256, 0, stream>>>(stats, g2, be2, bnAB, N, 128);

    // L3: GEMM (BN2 fused) -> P3 [N,64], aggregate -> Z3
    mgemm_kernel<128, 4, true><<<gb, 256, 0, stream>>>(hC, W3t, bnAB, pa, hD1, N, 64);
    aggh64_kernel<<<ab, 256, 0, stream>>>(hD1, hD2, row_ptr, colidx, dinv, N);
    hipMemsetAsync(stats, 0, 512 * 4, stream);
    stats2_kernel<64><<<512, 256, 0, stream>>>(hD2, stats, N);
    bnfin_kernel<<<1, 256, 0, stream>>>(stats, g3, be3, bnAB, N, 64);

    // L4: GEMM (BN3 fused) -> P4 [N,40], aggregate + b4 + log_softmax -> out (f32)
    mgemm_kernel<64, 3, true><<<gb, 256, 0, stream>>>(hD2, W4t, bnAB, pa, hE, N, 40);
    aggh_softmax_kernel<<<ab, 256, 0, stream>>>(hE, (float*)d_out, row_ptr, colidx, dinv, b4, N);
}

// Round 9
// 350.489 us; speedup vs baseline: 2.1608x; 1.1874x over previous
//
#include <hip/hip_runtime.h>
#include <cstdint>
#include <cmath>

typedef _Float16 half_t;
typedef _Float16 h2 __attribute__((ext_vector_type(2)));
typedef _Float16 h8 __attribute__((ext_vector_type(8)));
typedef float f4 __attribute__((ext_vector_type(4)));

// ================= CSR build: bucketed radix partition by dst>>8 =================
// Requires N <= 65536 (node ids packed in 16 bits) and NB <= 256 (host sizes chunk).
// hcnt layout is BUCKET-MAJOR: hcnt[bucket * NB + block].

// P1: per-(block,bucket) histogram
__global__ __launch_bounds__(256) void csr_hist_kernel(const int* __restrict__ ei_dst,
                                                       int* __restrict__ hcnt,
                                                       int E, int B, int NB, int chunk) {
    __shared__ int hist[256];
    int t = threadIdx.x;
    hist[t] = 0;
    __syncthreads();
    int base = blockIdx.x * chunk;
    int lim = min(base + chunk, E);
    for (int e = base + t; e < lim; e += 256) {
        int dst = ei_dst[e];
        atomicAdd(&hist[dst >> 8], 1);
    }
    __syncthreads();
    if (t < B) hcnt[t * NB + blockIdx.x] = hist[t];
}

// P2a: one block per bucket: exclusive scan of that bucket's per-block counts
__global__ __launch_bounds__(256) void csr_bscan_kernel(int* __restrict__ hcnt,
                                                        int* __restrict__ btot, int NB) {
    __shared__ int sh[256];
    int b = blockIdx.x, t = threadIdx.x;
    int v = (t < NB) ? hcnt[b * NB + t] : 0;
    sh[t] = v;
    __syncthreads();
    for (int off = 1; off < 256; off <<= 1) {
        int u = (t >= off) ? sh[t - off] : 0;
        __syncthreads();
        sh[t] += u;
        __syncthreads();
    }
    if (t < NB) hcnt[b * NB + t] = sh[t] - v;  // local exclusive prefix
    if (t == 255) btot[b] = sh[255];
}

// P2b: single block: exclusive scan of bucket totals -> edge_base (B <= 256)
__global__ __launch_bounds__(256) void csr_ebase_kernel(const int* __restrict__ btot,
                                                        int* __restrict__ edge_base,
                                                        int* __restrict__ row_ptr,
                                                        int B, int E, int n) {
    __shared__ int sh[256];
    int t = threadIdx.x;
    int v = (t < B) ? btot[t] : 0;
    sh[t] = v;
    __syncthreads();
    for (int off = 1; off < 256; off <<= 1) {
        int u = (t >= off) ? sh[t - off] : 0;
        __syncthreads();
        sh[t] += u;
        __syncthreads();
    }
    if (t < B) edge_base[t] = sh[t] - v;
    if (t == 0) {
        edge_base[B] = E;
        row_ptr[n] = E;
    }
}

// P3: partition edges into bucket-contiguous ebuf, packed (dstl<<16)|src
__global__ __launch_bounds__(256) void csr_part_kernel(const int* __restrict__ ei,
                                                       const int* __restrict__ hcnt,
                                                       const int* __restrict__ edge_base,
                                                       unsigned int* __restrict__ ebuf,
                                                       int E, int B, int NB, int chunk) {
    __shared__ int lcur[256];
    int t = threadIdx.x;
    if (t < B) lcur[t] = edge_base[t] + hcnt[t * NB + blockIdx.x];
    __syncthreads();
    int base = blockIdx.x * chunk;
    int lim = min(base + chunk, E);
    for (int e = base + t; e < lim; e += 256) {
        int src = ei[e];
        int dst = ei[E + e];
        int b = dst >> 8;
        int pos = atomicAdd(&lcur[b], 1);
        ebuf[pos] = ((unsigned int)(dst & 255) << 16) | (unsigned int)src;
    }
}

// P4: one block per bucket: LDS count -> scan -> row_ptr/dinv/fill (ushort colidx)
__global__ __launch_bounds__(256) void csr_fill_kernel(const unsigned int* __restrict__ ebuf,
                                                       const int* __restrict__ edge_base,
                                                       int* __restrict__ row_ptr,
                                                       float* __restrict__ dinv,
                                                       unsigned short* __restrict__ colidx,
                                                       int n) {
    __shared__ int cnt[256];
    __shared__ int sc[256];
    __shared__ int cur[256];
    int b = blockIdx.x;
    int t = threadIdx.x;
    int seg_beg = edge_base[b];
    int seg_end = edge_base[b + 1];
    cnt[t] = 0;
    __syncthreads();
    for (int e = seg_beg + t; e < seg_end; e += 256)
        atomicAdd(&cnt[ebuf[e] >> 16], 1);
    __syncthreads();
    sc[t] = cnt[t];
    __syncthreads();
    for (int off = 1; off < 256; off <<= 1) {
        int u = (t >= off) ? sc[t - off] : 0;
        __syncthreads();
        sc[t] += u;
        __syncthreads();
    }
    int excl = seg_beg + sc[t] - cnt[t];
    int node = (b << 8) + t;
    if (node < n) {
        row_ptr[node] = excl;
        dinv[node] = rsqrtf((float)cnt[t] + 1.0f);
    }
    cur[t] = excl;
    __syncthreads();
    for (int e = seg_beg + t; e < seg_end; e += 256) {
        unsigned int p = ebuf[e];
        int pos = atomicAdd(&cur[p >> 16], 1);
        colidx[pos] = (unsigned short)(p & 0xffff);
    }
}

// ---------------- conversions ----------------

__global__ void f2h_kernel(const float* __restrict__ x, half_t* __restrict__ xh, int total4) {
    int i = blockIdx.x * blockDim.x + threadIdx.x;
    if (i < total4) {
        float4 v = *(const float4*)&x[i * 4];
        half_t* p = xh + (size_t)i * 4;
        p[0] = (half_t)v.x; p[1] = (half_t)v.y; p[2] = (half_t)v.z; p[3] = (half_t)v.w;
    }
}

// Wt[n][k] = W[k][n], fp16, n zero-padded to Ncp
__global__ void wt_kernel(const float* __restrict__ W, half_t* __restrict__ Wt,
                          int K, int Nc, int Ncp) {
    int idx = blockIdx.x * blockDim.x + threadIdx.x;
    if (idx >= Ncp * K) return;
    int n = idx / K, k = idx - n * K;
    Wt[idx] = (n < Nc) ? (half_t)W[(size_t)k * Nc + n] : (half_t)0.f;
}

// ------- aggregation (fp16): out[d] = dinv[d]*(sum dinv[s]*in[s] + dinv[d]*in[d]) --------
// One 64-lane wave per node, 4 nodes per block; edge loop unrolled x4 for MLP (G7).

__global__ __launch_bounds__(256) void aggh128_kernel(const half_t* __restrict__ in,
                                                      half_t* __restrict__ out,
                                                      const int* __restrict__ row_ptr,
                                                      const unsigned short* __restrict__ colidx,
                                                      const float* __restrict__ dinv, int n) {
    int node = blockIdx.x * 4 + (threadIdx.x >> 6);
    if (node >= n) return;
    int c = threadIdx.x & 63;  // h2 per lane
    float dv = dinv[node];
    h2 self = *(const h2*)(in + (size_t)node * 128 + 2 * c);
    float acc0 = dv * (float)self[0], acc1 = dv * (float)self[1];
    int beg = row_ptr[node], end = row_ptr[node + 1];
    int k = beg;
    for (; k + 3 < end; k += 4) {
        int s0 = colidx[k], s1 = colidx[k + 1], s2 = colidx[k + 2], s3 = colidx[k + 3];
        float d0 = dinv[s0], d1 = dinv[s1], d2 = dinv[s2], d3 = dinv[s3];
        h2 v0 = *(const h2*)(in + (size_t)s0 * 128 + 2 * c);
        h2 v1 = *(const h2*)(in + (size_t)s1 * 128 + 2 * c);
        h2 v2 = *(const h2*)(in + (size_t)s2 * 128 + 2 * c);
        h2 v3 = *(const h2*)(in + (size_t)s3 * 128 + 2 * c);
        acc0 = fmaf(d0, (float)v0[0], acc0); acc1 = fmaf(d0, (float)v0[1], acc1);
        acc0 = fmaf(d1, (float)v1[0], acc0); acc1 = fmaf(d1, (float)v1[1], acc1);
        acc0 = fmaf(d2, (float)v2[0], acc0); acc1 = fmaf(d2, (float)v2[1], acc1);
        acc0 = fmaf(d3, (float)v3[0], acc0); acc1 = fmaf(d3, (float)v3[1], acc1);
    }
    for (; k < end; ++k) {
        int s = colidx[k];
        float ds = dinv[s];
        h2 v = *(const h2*)(in + (size_t)s * 128 + 2 * c);
        acc0 = fmaf(ds, (float)v[0], acc0);
        acc1 = fmaf(ds, (float)v[1], acc1);
    }
    h2 r;
    r[0] = (half_t)(dv * acc0);
    r[1] = (half_t)(dv * acc1);
    *(h2*)(out + (size_t)node * 128 + 2 * c) = r;
}

__global__ __launch_bounds__(256) void aggh64_kernel(const half_t* __restrict__ in,
                                                     half_t* __restrict__ out,
                                                     const int* __restrict__ row_ptr,
                                                     const unsigned short* __restrict__ colidx,
                                                     const float* __restrict__ dinv, int n) {
    int node = blockIdx.x * 4 + (threadIdx.x >> 6);
    if (node >= n) return;
    int c = threadIdx.x & 63;
    float dv = dinv[node];
    float acc = dv * (float)in[(size_t)node * 64 + c];
    int beg = row_ptr[node], end = row_ptr[node + 1];
    int k = beg;
    for (; k + 3 < end; k += 4) {
        int s0 = colidx[k], s1 = colidx[k + 1], s2 = colidx[k + 2], s3 = colidx[k + 3];
        float d0 = dinv[s0], d1 = dinv[s1], d2 = dinv[s2], d3 = dinv[s3];
        float v0 = (float)in[(size_t)s0 * 64 + c];
        float v1 = (float)in[(size_t)s1 * 64 + c];
        float v2 = (float)in[(size_t)s2 * 64 + c];
        float v3 = (float)in[(size_t)s3 * 64 + c];
        acc = fmaf(d0, v0, acc);
        acc = fmaf(d1, v1, acc);
        acc = fmaf(d2, v2, acc);
        acc = fmaf(d3, v3, acc);
    }
    for (; k < end; ++k) {
        int s = colidx[k];
        acc = fmaf(dinv[s], (float)in[(size_t)s * 64 + c], acc);
    }
    out[(size_t)node * 64 + c] = (half_t)(dv * acc);
}

// final layer: aggregate (F=40) + b4 + log_softmax, one wave per node, 4 nodes/block
__global__ __launch_bounds__(256) void aggh_softmax_kernel(const half_t* __restrict__ in,
                                                           float* __restrict__ out,
                                                           const int* __restrict__ row_ptr,
                                                           const unsigned short* __restrict__ colidx,
                                                           const float* __restrict__ dinv,
                                                           const float* __restrict__ b4, int n) {
    int node = blockIdx.x * 4 + (threadIdx.x >> 6);
    if (node >= n) return;
    int c = threadIdx.x & 63;  // 40 active
    float dv = dinv[node];
    float acc = 0.f;
    if (c < 40) acc = dv * (float)in[(size_t)node * 40 + c];
    int beg = row_ptr[node], end = row_ptr[node + 1];
    int k = beg;
    for (; k + 3 < end; k += 4) {
        int s0 = colidx[k], s1 = colidx[k + 1], s2 = colidx[k + 2], s3 = colidx[k + 3];
        float d0 = dinv[s0], d1 = dinv[s1], d2 = dinv[s2], d3 = dinv[s3];
        if (c < 40) {
            float v0 = (float)in[(size_t)s0 * 40 + c];
            float v1 = (float)in[(size_t)s1 * 40 + c];
            float v2 = (float)in[(size_t)s2 * 40 + c];
            float v3 = (float)in[(size_t)s3 * 40 + c];
            acc = fmaf(d0, v0, acc);
            acc = fmaf(d1, v1, acc);
            acc = fmaf(d2, v2, acc);
            acc = fmaf(d3, v3, acc);
        }
    }
    for (; k < end; ++k) {
        int s = colidx[k];
        if (c < 40) acc = fmaf(dinv[s], (float)in[(size_t)s * 40 + c], acc);
    }
    float z = (c < 40) ? (dv * acc + b4[c]) : -INFINITY;
    float m = z;
#pragma unroll
    for (int off = 32; off > 0; off >>= 1) m = fmaxf(m, __shfl_xor(m, off, 64));
    float e = (c < 40) ? expf(z - m) : 0.f;
    float s = e;
#pragma unroll
    for (int off = 32; off > 0; off >>= 1) s += __shfl_xor(s, off, 64);
    if (c < 40) out[(size_t)node * 40 + c] = z - m - logf(s);
}

// ---------------- MFMA GEMM ----------------

template <int K, int NT, bool FUSE>
__global__ __launch_bounds__(256) void mgemm_kernel(const half_t* __restrict__ A,
                                                    const half_t* __restrict__ Wt,  // [NT*16][K]
                                                    const float* __restrict__ AB,
                                                    const float* __restrict__ pa,
                                                    half_t* __restrict__ C,
                                                    int M, int Nc) {
    int wave = threadIdx.x >> 6;
    int lane = threadIdx.x & 63;
    int r0 = blockIdx.x * 64 + wave * 16;
    int arow = r0 + (lane & 15);
    int kgrp = lane >> 4;
    float alpha = FUSE ? pa[0] : 0.f;

    h8 af[K / 32];
    bool rowok = (arow < M);
    const half_t* Ap = A + (size_t)arow * K + kgrp * 8;
#pragma unroll
    for (int kk = 0; kk < K / 32; ++kk) {
        h8 v;
        if (rowok) {
            v = *(const h8*)(Ap + kk * 32);
        } else {
#pragma unroll
            for (int j = 0; j < 8; ++j) v[j] = (half_t)0.f;
        }
        if (FUSE) {
            int kb = kk * 32 + kgrp * 8;
#pragma unroll
            for (int j = 0; j < 8; ++j) {
                float u = (float)v[j] * AB[kb + j] + AB[256 + kb + j];
                u = (u >= 0.f) ? u : alpha * u;
                v[j] = (half_t)u;
            }
        }
        af[kk] = v;
    }

#pragma unroll 1
    for (int nt = 0; nt < NT; ++nt) {
        f4 acc = {0.f, 0.f, 0.f, 0.f};
        const half_t* Wp = Wt + (size_t)(nt * 16 + (lane & 15)) * K + kgrp * 8;
#pragma unroll
        for (int kk = 0; kk < K / 32; ++kk) {
            h8 bf = *(const h8*)(Wp + kk * 32);
            acc = __builtin_amdgcn_mfma_f32_16x16x32_f16(af[kk], bf, acc, 0, 0, 0);
        }
        int col = nt * 16 + (lane & 15);
        if (col < Nc) {
#pragma unroll
            for (int j = 0; j < 4; ++j) {
                int row = r0 + kgrp * 4 + j;
                if (row < M) C[(size_t)row * Nc + col] = (half_t)acc[j];
            }
        }
    }
}

// ---------------- BatchNorm stats ----------------

template <int F>
__global__ __launch_bounds__(256) void stats2_kernel(const half_t* __restrict__ z,
                                                     float* __restrict__ sums, int n) {
    constexpr int CB = F / 8;
    constexpr int RG = 256 / CB;
    __shared__ float red[256][16];
    int t = threadIdx.x;
    int cb = t % CB;
    int rg = t / CB;
    float sm[8], sq[8];
#pragma unroll
    for (int j = 0; j < 8; ++j) { sm[j] = 0.f; sq[j] = 0.f; }
    for (int r = blockIdx.x * RG + rg; r < n; r += gridDim.x * RG) {
        h8 v = *(const h8*)(z + (size_t)r * F + cb * 8);
#pragma unroll
        for (int j = 0; j < 8; ++j) {
            float f = (float)v[j];
            sm[j] += f;
            sq[j] = fmaf(f, f, sq[j]);
        }
    }
#pragma unroll
    for (int j = 0; j < 8; ++j) { red[t][j] = sm[j]; red[t][8 + j] = sq[j]; }
    __syncthreads();
    for (int o = t; o < 2 * F; o += 256) {
        int c = o % F, kind = o / F;
        int cbo = c >> 3, ci = (c & 7) + kind * 8;
        float v = 0.f;
#pragma unroll
        for (int g = 0; g < RG; ++g) v += red[g * CB + cbo][ci];
        atomicAdd(&sums[kind * 256 + c], v);
    }
}

__global__ void bnfin_kernel(const float* __restrict__ sums, const float* __restrict__ g,
                             const float* __restrict__ be, float* __restrict__ AB, int n, int F) {
    int c = threadIdx.x;
    if (c >= F) return;
    float mean = sums[c] / (float)n;
    float var = sums[256 + c] / (float)n - mean * mean;
    float rstd = rsqrtf(var + 1e-5f);
    float sc = g[c] * rstd;
    AB[c] = sc;
    AB[256 + c] = be[c] - mean * sc;
}

// ---------------- launch ----------------

extern "C" void kernel_launch(void* const* d_in, const int* in_sizes, int n_in,
                              void* d_out, int out_size, void* d_ws, size_t ws_size,
                              hipStream_t stream) {
    const float* x   = (const float*)d_in[0];
    const int*   ei  = (const int*)d_in[1];
    const float* W1  = (const float*)d_in[2];
    const float* g1  = (const float*)d_in[4];
    const float* be1 = (const float*)d_in[5];
    const float* W2  = (const float*)d_in[6];
    const float* g2  = (const float*)d_in[8];
    const float* be2 = (const float*)d_in[9];
    const float* W3  = (const float*)d_in[10];
    const float* g3  = (const float*)d_in[12];
    const float* be3 = (const float*)d_in[13];
    const float* W4  = (const float*)d_in[14];
    const float* b4  = (const float*)d_in[15];
    const float* pa  = (const float*)d_in[16];
    // b1,b2,b3 dropped: constants before BatchNorm cancel exactly in mean subtraction.

    int N = in_sizes[0] / 128;
    int E = in_sizes[1] / 2;
    int B = (N + 255) >> 8;                         // dst buckets (<=256 since N<=65536)
    int chunk = (((E + 255) / 256) + 255) & ~255;   // edges/block so that NB <= 256
    int NB = (E + chunk - 1) / chunk;               // hist/partition blocks

    char* ws = (char*)d_ws;
    size_t off = 0;
    auto carve = [&](size_t bytes) -> char* {
        char* p = ws + off;
        off += (bytes + 255) & ~(size_t)255;
        return p;
    };
    float*          dinv      = (float*)carve((size_t)N * 4);
    int*            row_ptr   = (int*)carve((size_t)(N + 1) * 4);
    int*            hcnt      = (int*)carve((size_t)B * NB * 4);  // bucket-major
    int*            btot      = (int*)carve((size_t)B * 4);
    int*            edge_base = (int*)carve((size_t)(B + 1) * 4);
    unsigned int*   ebuf      = (unsigned int*)carve((size_t)E * 4);
    unsigned short* colidx    = (unsigned short*)carve((size_t)E * 2);
    float*          stats     = (float*)carve(512 * 4);
    float*          bnAB      = (float*)carve(512 * 4);
    half_t* W1t = (half_t*)carve((size_t)256 * 128 * 2);
    half_t* W2t = (half_t*)carve((size_t)128 * 256 * 2);
    half_t* W3t = (half_t*)carve((size_t)64 * 128 * 2);
    half_t* W4t = (half_t*)carve((size_t)48 * 64 * 2);  // padded to 48 cols
    half_t* hA  = (half_t*)carve((size_t)N * 256 * 2);  // Z1
    half_t* hB  = (half_t*)carve((size_t)N * 128 * 2);  // xh, P2
    half_t* hC  = (half_t*)carve((size_t)N * 128 * 2);  // P1, Z2
    half_t* hD1 = (half_t*)carve((size_t)N * 64 * 2);   // P3
    half_t* hD2 = (half_t*)carve((size_t)N * 64 * 2);   // Z3
    half_t* hE  = (half_t*)carve((size_t)N * 40 * 2);   // P4
    (void)n_in; (void)out_size; (void)ws_size;

    // CSR build (bucketed; all passes parallel)
    csr_hist_kernel<<<NB, 256, 0, stream>>>(ei + E, hcnt, E, B, NB, chunk);
    csr_bscan_kernel<<<B, 256, 0, stream>>>(hcnt, btot, NB);
    csr_ebase_kernel<<<1, 256, 0, stream>>>(btot, edge_base, row_ptr, B, E, N);
    csr_part_kernel<<<NB, 256, 0, stream>>>(ei, hcnt, edge_base, ebuf, E, B, NB, chunk);
    csr_fill_kernel<<<B, 256, 0, stream>>>(ebuf, edge_base, row_ptr, dinv, colidx, N);

    // weight convert+transpose (fp16)
    wt_kernel<<<(256 * 128 + 255) / 256, 256, 0, stream>>>(W1, W1t, 128, 256, 256);
    wt_kernel<<<(128 * 256 + 255) / 256, 256, 0, stream>>>(W2, W2t, 256, 128, 128);
    wt_kernel<<<(64 * 128 + 255) / 256, 256, 0, stream>>>(W3, W3t, 128, 64, 64);
    wt_kernel<<<(48 * 64 + 255) / 256, 256, 0, stream>>>(W4, W4t, 64, 40, 48);

    int gb = (N + 63) / 64;   // mgemm blocks
    int ab = (N + 3) / 4;     // agg blocks (4 nodes each)

    // L1: x->fp16, aggregate(128), MFMA GEMM -> Z1 fp16 [N,256]
    f2h_kernel<<<(N * 128 / 4 + 255) / 256, 256, 0, stream>>>(x, hB, N * 128 / 4);
    aggh128_kernel<<<ab, 256, 0, stream>>>(hB, hC, row_ptr, colidx, dinv, N);
    mgemm_kernel<128, 16, false><<<gb, 256, 0, stream>>>(hC, W1t, nullptr, nullptr, hA, N, 256);
    hipMemsetAsync(stats, 0, 512 * 4, stream);
    stats2_kernel<256><<<512, 256, 0, stream>>>(hA, stats, N);
    bnfin_kernel<<<1, 256, 0, stream>>>(stats, g1, be1, bnAB, N, 256);

    // L2: GEMM (BN1+PReLU fused) -> P2 fp16 [N,128], aggregate -> Z2
    mgemm_kernel<256, 8, true><<<gb, 256, 0, stream>>>(hA, W2t, bnAB, pa, hB, N, 128);
    aggh128_kernel<<<ab, 256, 0, stream>>>(hB, hC, row_ptr, colidx, dinv, N);
    hipMemsetAsync(stats, 0, 512 * 4, stream);
    stats2_kernel<128><<<512, 256, 0, stream>>>(hC, stats, N);
    bnfin_kernel<<<1, 256, 0, stream>>>(stats, g2, be2, bnAB, N, 128);

    // L3: GEMM (BN2 fused) -> P3 [N,64], aggregate -> Z3
    mgemm_kernel<128, 4, true><<<gb, 256, 0, stream>>>(hC, W3t, bnAB, pa, hD1, N, 64);
    aggh64_kernel<<<ab, 256, 0, stream>>>(hD1, hD2, row_ptr, colidx, dinv, N);
    hipMemsetAsync(stats, 0, 512 * 4, stream);
    stats2_kernel<64><<<512, 256, 0, stream>>>(hD2, stats, N);
    bnfin_kernel<<<1, 256, 0, stream>>>(stats, g3, be3, bnAB, N, 64);

    // L4: GEMM (BN3 fused) -> P4 [N,40], aggregate + b4 + log_softmax -> out (f32)
    mgemm_kernel<64, 3, true><<<gb, 256, 0, stream>>>(hD2, W4t, bnAB, pa, hE, N, 40);
    aggh_softmax_kernel<<<ab, 256, 0, stream>>>(hE, (float*)d_out, row_ptr, colidx, dinv, b4, N);
}

// Round 10
// 317.000 us; speedup vs baseline: 2.3891x; 1.1056x over previous
//
#include <hip/hip_runtime.h>
#include <cstdint>
#include <cmath>

typedef _Float16 half_t;
typedef _Float16 h2 __attribute__((ext_vector_type(2)));
typedef _Float16 h8 __attribute__((ext_vector_type(8)));
typedef float f4 __attribute__((ext_vector_type(4)));

// ================= CSR build: bucketed radix partition by dst>>8 =================
// Requires N <= 65536 (node ids packed in 16 bits) and NB <= 256 (host sizes chunk).
// hcnt layout is BUCKET-MAJOR: hcnt[bucket * NB + block].

__global__ __launch_bounds__(256) void csr_hist_kernel(const int* __restrict__ ei_dst,
                                                       int* __restrict__ hcnt,
                                                       int E, int B, int NB, int chunk) {
    __shared__ int hist[256];
    int t = threadIdx.x;
    hist[t] = 0;
    __syncthreads();
    int base = blockIdx.x * chunk;
    int lim = min(base + chunk, E);
    for (int e = base + t; e < lim; e += 256) {
        int dst = ei_dst[e];
        atomicAdd(&hist[dst >> 8], 1);
    }
    __syncthreads();
    if (t < B) hcnt[t * NB + blockIdx.x] = hist[t];
}

__global__ __launch_bounds__(256) void csr_bscan_kernel(int* __restrict__ hcnt,
                                                        int* __restrict__ btot, int NB) {
    __shared__ int sh[256];
    int b = blockIdx.x, t = threadIdx.x;
    int v = (t < NB) ? hcnt[b * NB + t] : 0;
    sh[t] = v;
    __syncthreads();
    for (int off = 1; off < 256; off <<= 1) {
        int u = (t >= off) ? sh[t - off] : 0;
        __syncthreads();
        sh[t] += u;
        __syncthreads();
    }
    if (t < NB) hcnt[b * NB + t] = sh[t] - v;  // local exclusive prefix
    if (t == 255) btot[b] = sh[255];
}

__global__ __launch_bounds__(256) void csr_ebase_kernel(const int* __restrict__ btot,
                                                        int* __restrict__ edge_base,
                                                        int* __restrict__ row_ptr,
                                                        int B, int E, int n) {
    __shared__ int sh[256];
    int t = threadIdx.x;
    int v = (t < B) ? btot[t] : 0;
    sh[t] = v;
    __syncthreads();
    for (int off = 1; off < 256; off <<= 1) {
        int u = (t >= off) ? sh[t - off] : 0;
        __syncthreads();
        sh[t] += u;
        __syncthreads();
    }
    if (t < B) edge_base[t] = sh[t] - v;
    if (t == 0) {
        edge_base[B] = E;
        row_ptr[n] = E;
    }
}

__global__ __launch_bounds__(256) void csr_part_kernel(const int* __restrict__ ei,
                                                       const int* __restrict__ hcnt,
                                                       const int* __restrict__ edge_base,
                                                       unsigned int* __restrict__ ebuf,
                                                       int E, int B, int NB, int chunk) {
    __shared__ int lcur[256];
    int t = threadIdx.x;
    if (t < B) lcur[t] = edge_base[t] + hcnt[t * NB + blockIdx.x];
    __syncthreads();
    int base = blockIdx.x * chunk;
    int lim = min(base + chunk, E);
    for (int e = base + t; e < lim; e += 256) {
        int src = ei[e];
        int dst = ei[E + e];
        int b = dst >> 8;
        int pos = atomicAdd(&lcur[b], 1);
        ebuf[pos] = ((unsigned int)(dst & 255) << 16) | (unsigned int)src;
    }
}

__global__ __launch_bounds__(256) void csr_fill_kernel(const unsigned int* __restrict__ ebuf,
                                                       const int* __restrict__ edge_base,
                                                       int* __restrict__ row_ptr,
                                                       float* __restrict__ dinv,
                                                       unsigned short* __restrict__ colidx,
                                                       int n) {
    __shared__ int cnt[256];
    __shared__ int sc[256];
    __shared__ int cur[256];
    int b = blockIdx.x;
    int t = threadIdx.x;
    int seg_beg = edge_base[b];
    int seg_end = edge_base[b + 1];
    cnt[t] = 0;
    __syncthreads();
    for (int e = seg_beg + t; e < seg_end; e += 256)
        atomicAdd(&cnt[ebuf[e] >> 16], 1);
    __syncthreads();
    sc[t] = cnt[t];
    __syncthreads();
    for (int off = 1; off < 256; off <<= 1) {
        int u = (t >= off) ? sc[t - off] : 0;
        __syncthreads();
        sc[t] += u;
        __syncthreads();
    }
    int excl = seg_beg + sc[t] - cnt[t];
    int node = (b << 8) + t;
    if (node < n) {
        row_ptr[node] = excl;
        dinv[node] = rsqrtf((float)cnt[t] + 1.0f);
    }
    cur[t] = excl;
    __syncthreads();
    for (int e = seg_beg + t; e < seg_end; e += 256) {
        unsigned int p = ebuf[e];
        int pos = atomicAdd(&cur[p >> 16], 1);
        colidx[pos] = (unsigned short)(p & 0xffff);
    }
}

// ---------------- conversions ----------------

__global__ void f2h_kernel(const float* __restrict__ x, half_t* __restrict__ xh, int total4) {
    int i = blockIdx.x * blockDim.x + threadIdx.x;
    if (i < total4) {
        float4 v = *(const float4*)&x[i * 4];
        half_t* p = xh + (size_t)i * 4;
        p[0] = (half_t)v.x; p[1] = (half_t)v.y; p[2] = (half_t)v.z; p[3] = (half_t)v.w;
    }
}

// Wt[n][k] = W[k][n], fp16, n zero-padded to Ncp
__global__ void wt_kernel(const float* __restrict__ W, half_t* __restrict__ Wt,
                          int K, int Nc, int Ncp) {
    int idx = blockIdx.x * blockDim.x + threadIdx.x;
    if (idx >= Ncp * K) return;
    int n = idx / K, k = idx - n * K;
    Wt[idx] = (n < Nc) ? (half_t)W[(size_t)k * Nc + n] : (half_t)0.f;
}

// ------- aggregation (fp16): out[d] = dinv[d]*(sum dinv[s]*in[s] + dinv[d]*in[d]) --------
// One 64-lane wave per node, 4 nodes per block; edge loop unrolled x4 for MLP (G7).

__global__ __launch_bounds__(256) void aggh128_kernel(const half_t* __restrict__ in,
                                                      half_t* __restrict__ out,
                                                      const int* __restrict__ row_ptr,
                                                      const unsigned short* __restrict__ colidx,
                                                      const float* __restrict__ dinv, int n) {
    int node = blockIdx.x * 4 + (threadIdx.x >> 6);
    if (node >= n) return;
    int c = threadIdx.x & 63;  // h2 per lane
    float dv = dinv[node];
    h2 self = *(const h2*)(in + (size_t)node * 128 + 2 * c);
    float acc0 = dv * (float)self[0], acc1 = dv * (float)self[1];
    int beg = row_ptr[node], end = row_ptr[node + 1];
    int k = beg;
    for (; k + 3 < end; k += 4) {
        int s0 = colidx[k], s1 = colidx[k + 1], s2 = colidx[k + 2], s3 = colidx[k + 3];
        float d0 = dinv[s0], d1 = dinv[s1], d2 = dinv[s2], d3 = dinv[s3];
        h2 v0 = *(const h2*)(in + (size_t)s0 * 128 + 2 * c);
        h2 v1 = *(const h2*)(in + (size_t)s1 * 128 + 2 * c);
        h2 v2 = *(const h2*)(in + (size_t)s2 * 128 + 2 * c);
        h2 v3 = *(const h2*)(in + (size_t)s3 * 128 + 2 * c);
        acc0 = fmaf(d0, (float)v0[0], acc0); acc1 = fmaf(d0, (float)v0[1], acc1);
        acc0 = fmaf(d1, (float)v1[0], acc0); acc1 = fmaf(d1, (float)v1[1], acc1);
        acc0 = fmaf(d2, (float)v2[0], acc0); acc1 = fmaf(d2, (float)v2[1], acc1);
        acc0 = fmaf(d3, (float)v3[0], acc0); acc1 = fmaf(d3, (float)v3[1], acc1);
    }
    for (; k < end; ++k) {
        int s = colidx[k];
        float ds = dinv[s];
        h2 v = *(const h2*)(in + (size_t)s * 128 + 2 * c);
        acc0 = fmaf(ds, (float)v[0], acc0);
        acc1 = fmaf(ds, (float)v[1], acc1);
    }
    h2 r;
    r[0] = (half_t)(dv * acc0);
    r[1] = (half_t)(dv * acc1);
    *(h2*)(out + (size_t)node * 128 + 2 * c) = r;
}

__global__ __launch_bounds__(256) void aggh64_kernel(const half_t* __restrict__ in,
                                                     half_t* __restrict__ out,
                                                     const int* __restrict__ row_ptr,
                                                     const unsigned short* __restrict__ colidx,
                                                     const float* __restrict__ dinv, int n) {
    int node = blockIdx.x * 4 + (threadIdx.x >> 6);
    if (node >= n) return;
    int c = threadIdx.x & 63;
    float dv = dinv[node];
    float acc = dv * (float)in[(size_t)node * 64 + c];
    int beg = row_ptr[node], end = row_ptr[node + 1];
    int k = beg;
    for (; k + 3 < end; k += 4) {
        int s0 = colidx[k], s1 = colidx[k + 1], s2 = colidx[k + 2], s3 = colidx[k + 3];
        float d0 = dinv[s0], d1 = dinv[s1], d2 = dinv[s2], d3 = dinv[s3];
        float v0 = (float)in[(size_t)s0 * 64 + c];
        float v1 = (float)in[(size_t)s1 * 64 + c];
        float v2 = (float)in[(size_t)s2 * 64 + c];
        float v3 = (float)in[(size_t)s3 * 64 + c];
        acc = fmaf(d0, v0, acc);
        acc = fmaf(d1, v1, acc);
        acc = fmaf(d2, v2, acc);
        acc = fmaf(d3, v3, acc);
    }
    for (; k < end; ++k) {
        int s = colidx[k];
        acc = fmaf(dinv[s], (float)in[(size_t)s * 64 + c], acc);
    }
    out[(size_t)node * 64 + c] = (half_t)(dv * acc);
}

// final layer: aggregate (F=40) + b4 + log_softmax, one wave per node, 4 nodes/block
__global__ __launch_bounds__(256) void aggh_softmax_kernel(const half_t* __restrict__ in,
                                                           float* __restrict__ out,
                                                           const int* __restrict__ row_ptr,
                                                           const unsigned short* __restrict__ colidx,
                                                           const float* __restrict__ dinv,
                                                           const float* __restrict__ b4, int n) {
    int node = blockIdx.x * 4 + (threadIdx.x >> 6);
    if (node >= n) return;
    int c = threadIdx.x & 63;  // 40 active
    float dv = dinv[node];
    float acc = 0.f;
    if (c < 40) acc = dv * (float)in[(size_t)node * 40 + c];
    int beg = row_ptr[node], end = row_ptr[node + 1];
    int k = beg;
    for (; k + 3 < end; k += 4) {
        int s0 = colidx[k], s1 = colidx[k + 1], s2 = colidx[k + 2], s3 = colidx[k + 3];
        float d0 = dinv[s0], d1 = dinv[s1], d2 = dinv[s2], d3 = dinv[s3];
        if (c < 40) {
            float v0 = (float)in[(size_t)s0 * 40 + c];
            float v1 = (float)in[(size_t)s1 * 40 + c];
            float v2 = (float)in[(size_t)s2 * 40 + c];
            float v3 = (float)in[(size_t)s3 * 40 + c];
            acc = fmaf(d0, v0, acc);
            acc = fmaf(d1, v1, acc);
            acc = fmaf(d2, v2, acc);
            acc = fmaf(d3, v3, acc);
        }
    }
    for (; k < end; ++k) {
        int s = colidx[k];
        if (c < 40) acc = fmaf(dinv[s], (float)in[(size_t)s * 40 + c], acc);
    }
    float z = (c < 40) ? (dv * acc + b4[c]) : -INFINITY;
    float m = z;
#pragma unroll
    for (int off = 32; off > 0; off >>= 1) m = fmaxf(m, __shfl_xor(m, off, 64));
    float e = (c < 40) ? expf(z - m) : 0.f;
    float s = e;
#pragma unroll
    for (int off = 32; off > 0; off >>= 1) s += __shfl_xor(s, off, 64);
    if (c < 40) out[(size_t)node * 40 + c] = z - m - logf(s);
}

// ---------------- MFMA GEMM v2: LDS-staged weights, grid-stride row tiles ----------------
// Wt staged once per block into LDS (chunk-major [k/8][row] layout: a wave's 16 B-frag
// reads spread over 8 distinct 16B slots instead of row-major's 4). Blocks grid-stride
// over 64-row tiles; B-frag reads become ds_read_b128, A streams from global.

template <int K, int NT, bool FUSE>
__global__ __launch_bounds__(256) void mgemm_kernel(const half_t* __restrict__ A,
                                                    const half_t* __restrict__ Wt,  // [NT*16][K]
                                                    const float* __restrict__ AB,
                                                    const float* __restrict__ pa,
                                                    half_t* __restrict__ C,
                                                    int M, int Nc, int nTiles) {
    constexpr int NR = NT * 16;     // weight rows (= output cols, padded)
    constexpr int CH = K / 8;       // 16B chunks per row (power of 2)
    constexpr int LOG_CH = (CH == 8) ? 3 : (CH == 16 ? 4 : 5);
    __shared__ half_t wlds[NR * K];  // <= 64KB

    // stage: global coalesced read, chunk-major LDS write
    for (int idx = threadIdx.x; idx < NR * CH; idx += 256) {
        int row = idx >> LOG_CH;
        int c = idx & (CH - 1);
        *(h8*)(wlds + ((size_t)c * NR + row) * 8) = *(const h8*)(Wt + (size_t)idx * 8);
    }
    int wave = threadIdx.x >> 6;
    int lane = threadIdx.x & 63;
    int l16 = lane & 15, kgrp = lane >> 4;
    float alpha = FUSE ? pa[0] : 0.f;
    __syncthreads();

    for (int tile = blockIdx.x; tile < nTiles; tile += gridDim.x) {
        int r0 = tile * 64 + wave * 16;
        int arow = r0 + l16;
        bool rowok = (arow < M);
        const half_t* Ap = A + (size_t)arow * K + kgrp * 8;
        h8 af[K / 32];
#pragma unroll
        for (int kk = 0; kk < K / 32; ++kk) {
            h8 v;
            if (rowok) {
                v = *(const h8*)(Ap + kk * 32);
            } else {
#pragma unroll
                for (int j = 0; j < 8; ++j) v[j] = (half_t)0.f;
            }
            if (FUSE) {
                int kb = kk * 32 + kgrp * 8;
#pragma unroll
                for (int j = 0; j < 8; ++j) {
                    float u = (float)v[j] * AB[kb + j] + AB[256 + kb + j];
                    u = (u >= 0.f) ? u : alpha * u;
                    v[j] = (half_t)u;
                }
            }
            af[kk] = v;
        }

        for (int nt = 0; nt < NT; ++nt) {
            f4 acc = {0.f, 0.f, 0.f, 0.f};
#pragma unroll
            for (int kk = 0; kk < K / 32; ++kk) {
                // chunk c = kk*4 + kgrp holds k = [kk*32+kgrp*8, +8) for row nt*16+l16
                h8 bf = *(const h8*)(wlds + ((size_t)(kk * 4 + kgrp) * NR + nt * 16 + l16) * 8);
                acc = __builtin_amdgcn_mfma_f32_16x16x32_f16(af[kk], bf, acc, 0, 0, 0);
            }
            int col = nt * 16 + l16;
            if (col < Nc) {
#pragma unroll
                for (int j = 0; j < 4; ++j) {
                    int row = r0 + kgrp * 4 + j;
                    if (row < M) C[(size_t)row * Nc + col] = (half_t)acc[j];
                }
            }
        }
    }
}

// ---------------- BatchNorm stats ----------------

template <int F>
__global__ __launch_bounds__(256) void stats2_kernel(const half_t* __restrict__ z,
                                                     float* __restrict__ sums, int n) {
    constexpr int CB = F / 8;
    constexpr int RG = 256 / CB;
    __shared__ float red[256][16];
    int t = threadIdx.x;
    int cb = t % CB;
    int rg = t / CB;
    float sm[8], sq[8];
#pragma unroll
    for (int j = 0; j < 8; ++j) { sm[j] = 0.f; sq[j] = 0.f; }
    for (int r = blockIdx.x * RG + rg; r < n; r += gridDim.x * RG) {
        h8 v = *(const h8*)(z + (size_t)r * F + cb * 8);
#pragma unroll
        for (int j = 0; j < 8; ++j) {
            float f = (float)v[j];
            sm[j] += f;
            sq[j] = fmaf(f, f, sq[j]);
        }
    }
#pragma unroll
    for (int j = 0; j < 8; ++j) { red[t][j] = sm[j]; red[t][8 + j] = sq[j]; }
    __syncthreads();
    for (int o = t; o < 2 * F; o += 256) {
        int c = o % F, kind = o / F;
        int cbo = c >> 3, ci = (c & 7) + kind * 8;
        float v = 0.f;
#pragma unroll
        for (int g = 0; g < RG; ++g) v += red[g * CB + cbo][ci];
        atomicAdd(&sums[kind * 256 + c], v);
    }
}

__global__ void bnfin_kernel(const float* __restrict__ sums, const float* __restrict__ g,
                             const float* __restrict__ be, float* __restrict__ AB, int n, int F) {
    int c = threadIdx.x;
    if (c >= F) return;
    float mean = sums[c] / (float)n;
    float var = sums[256 + c] / (float)n - mean * mean;
    float rstd = rsqrtf(var + 1e-5f);
    float sc = g[c] * rstd;
    AB[c] = sc;
    AB[256 + c] = be[c] - mean * sc;
}

// ---------------- launch ----------------

extern "C" void kernel_launch(void* const* d_in, const int* in_sizes, int n_in,
                              void* d_out, int out_size, void* d_ws, size_t ws_size,
                              hipStream_t stream) {
    const float* x   = (const float*)d_in[0];
    const int*   ei  = (const int*)d_in[1];
    const float* W1  = (const float*)d_in[2];
    const float* g1  = (const float*)d_in[4];
    const float* be1 = (const float*)d_in[5];
    const float* W2  = (const float*)d_in[6];
    const float* g2  = (const float*)d_in[8];
    const float* be2 = (const float*)d_in[9];
    const float* W3  = (const float*)d_in[10];
    const float* g3  = (const float*)d_in[12];
    const float* be3 = (const float*)d_in[13];
    const float* W4  = (const float*)d_in[14];
    const float* b4  = (const float*)d_in[15];
    const float* pa  = (const float*)d_in[16];
    // b1,b2,b3 dropped: constants before BatchNorm cancel exactly in mean subtraction.

    int N = in_sizes[0] / 128;
    int E = in_sizes[1] / 2;
    int B = (N + 255) >> 8;                         // dst buckets (<=256 since N<=65536)
    int chunk = (((E + 255) / 256) + 255) & ~255;   // edges/block so that NB <= 256
    int NB = (E + chunk - 1) / chunk;               // hist/partition blocks

    char* ws = (char*)d_ws;
    size_t off = 0;
    auto carve = [&](size_t bytes) -> char* {
        char* p = ws + off;
        off += (bytes + 255) & ~(size_t)255;
        return p;
    };
    float*          dinv      = (float*)carve((size_t)N * 4);
    int*            row_ptr   = (int*)carve((size_t)(N + 1) * 4);
    int*            hcnt      = (int*)carve((size_t)B * NB * 4);  // bucket-major
    int*            btot      = (int*)carve((size_t)B * 4);
    int*            edge_base = (int*)carve((size_t)(B + 1) * 4);
    unsigned int*   ebuf      = (unsigned int*)carve((size_t)E * 4);
    unsigned short* colidx    = (unsigned short*)carve((size_t)E * 2);
    float*          stats     = (float*)carve(512 * 4);
    float*          bnAB      = (float*)carve(512 * 4);
    half_t* W1t = (half_t*)carve((size_t)256 * 128 * 2);
    half_t* W2t = (half_t*)carve((size_t)128 * 256 * 2);
    half_t* W3t = (half_t*)carve((size_t)64 * 128 * 2);
    half_t* W4t = (half_t*)carve((size_t)48 * 64 * 2);  // padded to 48 cols
    half_t* hA  = (half_t*)carve((size_t)N * 256 * 2);  // Z1
    half_t* hB  = (half_t*)carve((size_t)N * 128 * 2);  // xh, P2
    half_t* hC  = (half_t*)carve((size_t)N * 128 * 2);  // P1, Z2
    half_t* hD1 = (half_t*)carve((size_t)N * 64 * 2);   // P3
    half_t* hD2 = (half_t*)carve((size_t)N * 64 * 2);   // Z3
    half_t* hE  = (half_t*)carve((size_t)N * 40 * 2);   // P4
    (void)n_in; (void)out_size; (void)ws_size;

    // CSR build (bucketed; all passes parallel)
    csr_hist_kernel<<<NB, 256, 0, stream>>>(ei + E, hcnt, E, B, NB, chunk);
    csr_bscan_kernel<<<B, 256, 0, stream>>>(hcnt, btot, NB);
    csr_ebase_kernel<<<1, 256, 0, stream>>>(btot, edge_base, row_ptr, B, E, N);
    csr_part_kernel<<<NB, 256, 0, stream>>>(ei, hcnt, edge_base, ebuf, E, B, NB, chunk);
    csr_fill_kernel<<<B, 256, 0, stream>>>(ebuf, edge_base, row_ptr, dinv, colidx, N);

    // weight convert+transpose (fp16)
    wt_kernel<<<(256 * 128 + 255) / 256, 256, 0, stream>>>(W1, W1t, 128, 256, 256);
    wt_kernel<<<(128 * 256 + 255) / 256, 256, 0, stream>>>(W2, W2t, 256, 128, 128);
    wt_kernel<<<(64 * 128 + 255) / 256, 256, 0, stream>>>(W3, W3t, 128, 64, 64);
    wt_kernel<<<(48 * 64 + 255) / 256, 256, 0, stream>>>(W4, W4t, 64, 40, 48);

    int nTiles = (N + 63) / 64;
    int gb = nTiles < 512 ? nTiles : 512;  // 2 blocks/CU (64KB LDS each)
    int ab = (N + 3) / 4;                  // agg blocks (4 nodes each)

    // L1: x->fp16, aggregate(128), MFMA GEMM -> Z1 fp16 [N,256]
    f2h_kernel<<<(N * 128 / 4 + 255) / 256, 256, 0, stream>>>(x, hB, N * 128 / 4);
    aggh128_kernel<<<ab, 256, 0, stream>>>(hB, hC, row_ptr, colidx, dinv, N);
    mgemm_kernel<128, 16, false><<<gb, 256, 0, stream>>>(hC, W1t, nullptr, nullptr, hA,
                                                         N, 256, nTiles);
    hipMemsetAsync(stats, 0, 512 * 4, stream);
    stats2_kernel<256><<<512, 256, 0, stream>>>(hA, stats, N);
    bnfin_kernel<<<1, 256, 0, stream>>>(stats, g1, be1, bnAB, N, 256);

    // L2: GEMM (BN1+PReLU fused) -> P2 fp16 [N,128], aggregate -> Z2
    mgemm_kernel<256, 8, true><<<gb, 256, 0, stream>>>(hA, W2t, bnAB, pa, hB, N, 128, nTiles);
    aggh128_kernel<<<ab, 256, 0, stream>>>(hB, hC, row_ptr, colidx, dinv, N);
    hipMemsetAsync(stats, 0, 512 * 4, stream);
    stats2_kernel<128><<<512, 256, 0, stream>>>(hC, stats, N);
    bnfin_kernel<<<1, 256, 0, stream>>>(stats, g2, be2, bnAB, N, 128);

    // L3: GEMM (BN2 fused) -> P3 [N,64], aggregate -> Z3
    mgemm_kernel<128, 4, true><<<gb, 256, 0, stream>>>(hC, W3t, bnAB, pa, hD1, N, 64, nTiles);
    aggh64_kernel<<<ab, 256, 0, stream>>>(hD1, hD2, row_ptr, colidx, dinv, N);
    hipMemsetAsync(stats, 0, 512 * 4, stream);
    stats2_kernel<64><<<512, 256, 0, stream>>>(hD2, stats, N);
    bnfin_kernel<<<1, 256, 0, stream>>>(stats, g3, be3, bnAB, N, 64);

    // L4: GEMM (BN3 fused) -> P4 [N,40], aggregate + b4 + log_softmax -> out (f32)
    mgemm_kernel<64, 3, true><<<gb, 256, 0, stream>>>(hD2, W4t, bnAB, pa, hE, N, 40, nTiles);
    aggh_softmax_kernel<<<ab, 256, 0, stream>>>(hE, (float*)d_out, row_ptr, colidx, dinv, b4, N);
}

// Round 11
// 298.171 us; speedup vs baseline: 2.5400x; 1.0631x over previous
//
#include <hip/hip_runtime.h>
#include <cstdint>
#include <cmath>

typedef _Float16 half_t;
typedef _Float16 h2 __attribute__((ext_vector_type(2)));
typedef _Float16 h8 __attribute__((ext_vector_type(8)));
typedef float f4 __attribute__((ext_vector_type(4)));

// ================= CSR build: bucketed radix partition by dst>>8 =================
// Requires N <= 65536 (node ids packed in 16 bits) and NB <= 256 (host sizes chunk).
// hcnt layout is BUCKET-MAJOR: hcnt[bucket * NB + block].

__global__ __launch_bounds__(256) void csr_hist_kernel(const int* __restrict__ ei_dst,
                                                       int* __restrict__ hcnt,
                                                       int E, int B, int NB, int chunk) {
    __shared__ int hist[256];
    int t = threadIdx.x;
    hist[t] = 0;
    __syncthreads();
    int base = blockIdx.x * chunk;
    int lim = min(base + chunk, E);
    for (int e = base + t; e < lim; e += 256) {
        int dst = ei_dst[e];
        atomicAdd(&hist[dst >> 8], 1);
    }
    __syncthreads();
    if (t < B) hcnt[t * NB + blockIdx.x] = hist[t];
}

__global__ __launch_bounds__(256) void csr_bscan_kernel(int* __restrict__ hcnt,
                                                        int* __restrict__ btot, int NB) {
    __shared__ int sh[256];
    int b = blockIdx.x, t = threadIdx.x;
    int v = (t < NB) ? hcnt[b * NB + t] : 0;
    sh[t] = v;
    __syncthreads();
    for (int off = 1; off < 256; off <<= 1) {
        int u = (t >= off) ? sh[t - off] : 0;
        __syncthreads();
        sh[t] += u;
        __syncthreads();
    }
    if (t < NB) hcnt[b * NB + t] = sh[t] - v;  // local exclusive prefix
    if (t == 255) btot[b] = sh[255];
}

__global__ __launch_bounds__(256) void csr_ebase_kernel(const int* __restrict__ btot,
                                                        int* __restrict__ edge_base,
                                                        int* __restrict__ row_ptr,
                                                        int B, int E, int n) {
    __shared__ int sh[256];
    int t = threadIdx.x;
    int v = (t < B) ? btot[t] : 0;
    sh[t] = v;
    __syncthreads();
    for (int off = 1; off < 256; off <<= 1) {
        int u = (t >= off) ? sh[t - off] : 0;
        __syncthreads();
        sh[t] += u;
        __syncthreads();
    }
    if (t < B) edge_base[t] = sh[t] - v;
    if (t == 0) {
        edge_base[B] = E;
        row_ptr[n] = E;
    }
}

__global__ __launch_bounds__(256) void csr_part_kernel(const int* __restrict__ ei,
                                                       const int* __restrict__ hcnt,
                                                       const int* __restrict__ edge_base,
                                                       unsigned int* __restrict__ ebuf,
                                                       int E, int B, int NB, int chunk) {
    __shared__ int lcur[256];
    int t = threadIdx.x;
    if (t < B) lcur[t] = edge_base[t] + hcnt[t * NB + blockIdx.x];
    __syncthreads();
    int base = blockIdx.x * chunk;
    int lim = min(base + chunk, E);
    for (int e = base + t; e < lim; e += 256) {
        int src = ei[e];
        int dst = ei[E + e];
        int b = dst >> 8;
        int pos = atomicAdd(&lcur[b], 1);
        ebuf[pos] = ((unsigned int)(dst & 255) << 16) | (unsigned int)src;
    }
}

__global__ __launch_bounds__(256) void csr_fill_kernel(const unsigned int* __restrict__ ebuf,
                                                       const int* __restrict__ edge_base,
                                                       int* __restrict__ row_ptr,
                                                       float* __restrict__ dinv,
                                                       unsigned short* __restrict__ colidx,
                                                       int n) {
    __shared__ int cnt[256];
    __shared__ int sc[256];
    __shared__ int cur[256];
    int b = blockIdx.x;
    int t = threadIdx.x;
    int seg_beg = edge_base[b];
    int seg_end = edge_base[b + 1];
    cnt[t] = 0;
    __syncthreads();
    for (int e = seg_beg + t; e < seg_end; e += 256)
        atomicAdd(&cnt[ebuf[e] >> 16], 1);
    __syncthreads();
    sc[t] = cnt[t];
    __syncthreads();
    for (int off = 1; off < 256; off <<= 1) {
        int u = (t >= off) ? sc[t - off] : 0;
        __syncthreads();
        sc[t] += u;
        __syncthreads();
    }
    int excl = seg_beg + sc[t] - cnt[t];
    int node = (b << 8) + t;
    if (node < n) {
        row_ptr[node] = excl;
        dinv[node] = rsqrtf((float)cnt[t] + 1.0f);
    }
    cur[t] = excl;
    __syncthreads();
    for (int e = seg_beg + t; e < seg_end; e += 256) {
        unsigned int p = ebuf[e];
        int pos = atomicAdd(&cur[p >> 16], 1);
        colidx[pos] = (unsigned short)(p & 0xffff);
    }
}

// ---------------- conversions ----------------

__global__ void f2h_kernel(const float* __restrict__ x, half_t* __restrict__ xh, int total4) {
    int i = blockIdx.x * blockDim.x + threadIdx.x;
    if (i < total4) {
        float4 v = *(const float4*)&x[i * 4];
        half_t* p = xh + (size_t)i * 4;
        p[0] = (half_t)v.x; p[1] = (half_t)v.y; p[2] = (half_t)v.z; p[3] = (half_t)v.w;
    }
}

// all 4 weight transposes in one launch. Wt[n][k] = W[k][n], n zero-padded.
__global__ __launch_bounds__(256) void wtall_kernel(const float* __restrict__ W1,
                                                    const float* __restrict__ W2,
                                                    const float* __restrict__ W3,
                                                    const float* __restrict__ W4,
                                                    half_t* __restrict__ W1t,
                                                    half_t* __restrict__ W2t,
                                                    half_t* __restrict__ W3t,
                                                    half_t* __restrict__ W4t) {
    int idx = blockIdx.x * blockDim.x + threadIdx.x;
    if (idx < 32768) {                       // W1 [128,256] -> W1t [256][128]
        int n = idx >> 7, k = idx & 127;
        W1t[idx] = (half_t)W1[k * 256 + n];
    } else if (idx < 65536) {                // W2 [256,128] -> W2t [128][256]
        int r = idx - 32768;
        int n = r >> 8, k = r & 255;
        W2t[r] = (half_t)W2[k * 128 + n];
    } else if (idx < 73728) {                // W3 [128,64] -> W3t [64][128]
        int r = idx - 65536;
        int n = r >> 7, k = r & 127;
        W3t[r] = (half_t)W3[k * 64 + n];
    } else if (idx < 77824) {                // W4 [64,40] -> W4t [64][64] zero-padded
        int r = idx - 73728;
        int n = r >> 6, k = r & 63;
        W4t[r] = (n < 40) ? (half_t)W4[k * 40 + n] : (half_t)0.f;
    }
}

// ------- aggregation (fp16): out[d] = dinv[d]*(sum dinv[s]*in[s] + dinv[d]*in[d]) --------
// One 64-lane wave per node, 4 nodes per block. Masked unroll-8: colidx is padded by
// 16 zeroed entries so all 8 loads always issue; out-of-row lanes get weight 0.
// -> constant 2-3 fully-pipelined gather steps per node, no serial remainder (G7).

__global__ __launch_bounds__(256) void aggh128_kernel(const half_t* __restrict__ in,
                                                      half_t* __restrict__ out,
                                                      const int* __restrict__ row_ptr,
                                                      const unsigned short* __restrict__ colidx,
                                                      const float* __restrict__ dinv, int n) {
    int node = blockIdx.x * 4 + (threadIdx.x >> 6);
    if (node >= n) return;
    int c = threadIdx.x & 63;  // h2 per lane
    float dv = dinv[node];
    h2 self = *(const h2*)(in + (size_t)node * 128 + 2 * c);
    float acc0 = dv * (float)self[0], acc1 = dv * (float)self[1];
    int beg = row_ptr[node], end = row_ptr[node + 1];
    for (int k = beg; k < end; k += 8) {
        int idx[8]; float w[8]; h2 v[8];
#pragma unroll
        for (int j = 0; j < 8; ++j) idx[j] = colidx[k + j];
#pragma unroll
        for (int j = 0; j < 8; ++j) w[j] = (k + j < end) ? dinv[idx[j]] : 0.f;
#pragma unroll
        for (int j = 0; j < 8; ++j) v[j] = *(const h2*)(in + (size_t)idx[j] * 128 + 2 * c);
#pragma unroll
        for (int j = 0; j < 8; ++j) {
            acc0 = fmaf(w[j], (float)v[j][0], acc0);
            acc1 = fmaf(w[j], (float)v[j][1], acc1);
        }
    }
    h2 r;
    r[0] = (half_t)(dv * acc0);
    r[1] = (half_t)(dv * acc1);
    *(h2*)(out + (size_t)node * 128 + 2 * c) = r;
}

__global__ __launch_bounds__(256) void aggh64_kernel(const half_t* __restrict__ in,
                                                     half_t* __restrict__ out,
                                                     const int* __restrict__ row_ptr,
                                                     const unsigned short* __restrict__ colidx,
                                                     const float* __restrict__ dinv, int n) {
    int node = blockIdx.x * 4 + (threadIdx.x >> 6);
    if (node >= n) return;
    int c = threadIdx.x & 63;
    float dv = dinv[node];
    float acc = dv * (float)in[(size_t)node * 64 + c];
    int beg = row_ptr[node], end = row_ptr[node + 1];
    for (int k = beg; k < end; k += 8) {
        int idx[8]; float w[8]; float v[8];
#pragma unroll
        for (int j = 0; j < 8; ++j) idx[j] = colidx[k + j];
#pragma unroll
        for (int j = 0; j < 8; ++j) w[j] = (k + j < end) ? dinv[idx[j]] : 0.f;
#pragma unroll
        for (int j = 0; j < 8; ++j) v[j] = (float)in[(size_t)idx[j] * 64 + c];
#pragma unroll
        for (int j = 0; j < 8; ++j) acc = fmaf(w[j], v[j], acc);
    }
    out[(size_t)node * 64 + c] = (half_t)(dv * acc);
}

// final layer: P4 padded [N,64] (cols 40+ zero) -> aggregate + b4 + log_softmax -> f32 out
// 32-lane mirrored halves load h2 (row = one aligned 128B line); masked unroll-8.
__global__ __launch_bounds__(256) void aggsm64_kernel(const half_t* __restrict__ in,
                                                      float* __restrict__ out,
                                                      const int* __restrict__ row_ptr,
                                                      const unsigned short* __restrict__ colidx,
                                                      const float* __restrict__ dinv,
                                                      const float* __restrict__ b4, int n) {
    int node = blockIdx.x * 4 + (threadIdx.x >> 6);
    if (node >= n) return;
    int c = threadIdx.x & 31;  // lanes 32-63 mirror lanes 0-31 (same addresses)
    float dv = dinv[node];
    h2 self = *(const h2*)(in + (size_t)node * 64 + 2 * c);
    float acc0 = dv * (float)self[0], acc1 = dv * (float)self[1];
    int beg = row_ptr[node], end = row_ptr[node + 1];
    for (int k = beg; k < end; k += 8) {
        int idx[8]; float w[8]; h2 v[8];
#pragma unroll
        for (int j = 0; j < 8; ++j) idx[j] = colidx[k + j];
#pragma unroll
        for (int j = 0; j < 8; ++j) w[j] = (k + j < end) ? dinv[idx[j]] : 0.f;
#pragma unroll
        for (int j = 0; j < 8; ++j) v[j] = *(const h2*)(in + (size_t)idx[j] * 64 + 2 * c);
#pragma unroll
        for (int j = 0; j < 8; ++j) {
            acc0 = fmaf(w[j], (float)v[j][0], acc0);
            acc1 = fmaf(w[j], (float)v[j][1], acc1);
        }
    }
    int col0 = 2 * c, col1 = 2 * c + 1;
    float z0 = (col0 < 40) ? (dv * acc0 + b4[col0]) : -INFINITY;
    float z1 = (col1 < 40) ? (dv * acc1 + b4[col1]) : -INFINITY;
    float m = fmaxf(z0, z1);
#pragma unroll
    for (int off = 16; off > 0; off >>= 1) m = fmaxf(m, __shfl_xor(m, off, 64));
    float e0 = (col0 < 40) ? expf(z0 - m) : 0.f;
    float e1 = (col1 < 40) ? expf(z1 - m) : 0.f;
    float s = e0 + e1;
#pragma unroll
    for (int off = 16; off > 0; off >>= 1) s += __shfl_xor(s, off, 64);
    float ls = logf(s);
    if (c < 20) {
        float2 r = make_float2(z0 - m - ls, z1 - m - ls);
        *(float2*)(out + (size_t)node * 40 + 2 * c) = r;
    }
}

// ---------------- MFMA GEMM v2: LDS-staged weights, grid-stride row tiles ----------------

template <int K, int NT, bool FUSE>
__global__ __launch_bounds__(256) void mgemm_kernel(const half_t* __restrict__ A,
                                                    const half_t* __restrict__ Wt,  // [NT*16][K]
                                                    const float* __restrict__ AB,
                                                    const float* __restrict__ pa,
                                                    half_t* __restrict__ C,
                                                    int M, int Nc, int nTiles) {
    constexpr int NR = NT * 16;     // weight rows (= output cols, padded)
    constexpr int CH = K / 8;       // 16B chunks per row (power of 2)
    constexpr int LOG_CH = (CH == 8) ? 3 : (CH == 16 ? 4 : 5);
    __shared__ half_t wlds[NR * K];  // <= 64KB

    // stage: global coalesced read, chunk-major LDS write
    for (int idx = threadIdx.x; idx < NR * CH; idx += 256) {
        int row = idx >> LOG_CH;
        int c = idx & (CH - 1);
        *(h8*)(wlds + ((size_t)c * NR + row) * 8) = *(const h8*)(Wt + (size_t)idx * 8);
    }
    int wave = threadIdx.x >> 6;
    int lane = threadIdx.x & 63;
    int l16 = lane & 15, kgrp = lane >> 4;
    float alpha = FUSE ? pa[0] : 0.f;
    __syncthreads();

    for (int tile = blockIdx.x; tile < nTiles; tile += gridDim.x) {
        int r0 = tile * 64 + wave * 16;
        int arow = r0 + l16;
        bool rowok = (arow < M);
        const half_t* Ap = A + (size_t)arow * K + kgrp * 8;
        h8 af[K / 32];
#pragma unroll
        for (int kk = 0; kk < K / 32; ++kk) {
            h8 v;
            if (rowok) {
                v = *(const h8*)(Ap + kk * 32);
            } else {
#pragma unroll
                for (int j = 0; j < 8; ++j) v[j] = (half_t)0.f;
            }
            if (FUSE) {
                int kb = kk * 32 + kgrp * 8;
#pragma unroll
                for (int j = 0; j < 8; ++j) {
                    float u = (float)v[j] * AB[kb + j] + AB[256 + kb + j];
                    u = (u >= 0.f) ? u : alpha * u;
                    v[j] = (half_t)u;
                }
            }
            af[kk] = v;
        }

        for (int nt = 0; nt < NT; ++nt) {
            f4 acc = {0.f, 0.f, 0.f, 0.f};
#pragma unroll
            for (int kk = 0; kk < K / 32; ++kk) {
                h8 bf = *(const h8*)(wlds + ((size_t)(kk * 4 + kgrp) * NR + nt * 16 + l16) * 8);
                acc = __builtin_amdgcn_mfma_f32_16x16x32_f16(af[kk], bf, acc, 0, 0, 0);
            }
            int col = nt * 16 + l16;
            if (col < Nc) {
#pragma unroll
                for (int j = 0; j < 4; ++j) {
                    int row = r0 + kgrp * 4 + j;
                    if (row < M) C[(size_t)row * Nc + col] = (half_t)acc[j];
                }
            }
        }
    }
}

// ---------------- BatchNorm stats ----------------

template <int F>
__global__ __launch_bounds__(256) void stats2_kernel(const half_t* __restrict__ z,
                                                     float* __restrict__ sums, int n) {
    constexpr int CB = F / 8;
    constexpr int RG = 256 / CB;
    __shared__ float red[256][16];
    int t = threadIdx.x;
    int cb = t % CB;
    int rg = t / CB;
    float sm[8], sq[8];
#pragma unroll
    for (int j = 0; j < 8; ++j) { sm[j] = 0.f; sq[j] = 0.f; }
    for (int r = blockIdx.x * RG + rg; r < n; r += gridDim.x * RG) {
        h8 v = *(const h8*)(z + (size_t)r * F + cb * 8);
#pragma unroll
        for (int j = 0; j < 8; ++j) {
            float f = (float)v[j];
            sm[j] += f;
            sq[j] = fmaf(f, f, sq[j]);
        }
    }
#pragma unroll
    for (int j = 0; j < 8; ++j) { red[t][j] = sm[j]; red[t][8 + j] = sq[j]; }
    __syncthreads();
    for (int o = t; o < 2 * F; o += 256) {
        int c = o % F, kind = o / F;
        int cbo = c >> 3, ci = (c & 7) + kind * 8;
        float v = 0.f;
#pragma unroll
        for (int g = 0; g < RG; ++g) v += red[g * CB + cbo][ci];
        atomicAdd(&sums[kind * 256 + c], v);
    }
}

__global__ void bnfin_kernel(const float* __restrict__ sums, const float* __restrict__ g,
                             const float* __restrict__ be, float* __restrict__ AB, int n, int F) {
    int c = threadIdx.x;
    if (c >= F) return;
    float mean = sums[c] / (float)n;
    float var = sums[256 + c] / (float)n - mean * mean;
    float rstd = rsqrtf(var + 1e-5f);
    float sc = g[c] * rstd;
    AB[c] = sc;
    AB[256 + c] = be[c] - mean * sc;
}

// ---------------- launch ----------------

extern "C" void kernel_launch(void* const* d_in, const int* in_sizes, int n_in,
                              void* d_out, int out_size, void* d_ws, size_t ws_size,
                              hipStream_t stream) {
    const float* x   = (const float*)d_in[0];
    const int*   ei  = (const int*)d_in[1];
    const float* W1  = (const float*)d_in[2];
    const float* g1  = (const float*)d_in[4];
    const float* be1 = (const float*)d_in[5];
    const float* W2  = (const float*)d_in[6];
    const float* g2  = (const float*)d_in[8];
    const float* be2 = (const float*)d_in[9];
    const float* W3  = (const float*)d_in[10];
    const float* g3  = (const float*)d_in[12];
    const float* be3 = (const float*)d_in[13];
    const float* W4  = (const float*)d_in[14];
    const float* b4  = (const float*)d_in[15];
    const float* pa  = (const float*)d_in[16];
    // b1,b2,b3 dropped: constants before BatchNorm cancel exactly in mean subtraction.

    int N = in_sizes[0] / 128;
    int E = in_sizes[1] / 2;
    int B = (N + 255) >> 8;                         // dst buckets (<=256 since N<=65536)
    int chunk = (((E + 255) / 256) + 255) & ~255;   // edges/block so that NB <= 256
    int NB = (E + chunk - 1) / chunk;               // hist/partition blocks

    char* ws = (char*)d_ws;
    size_t off = 0;
    auto carve = [&](size_t bytes) -> char* {
        char* p = ws + off;
        off += (bytes + 255) & ~(size_t)255;
        return p;
    };
    float*          dinv      = (float*)carve((size_t)N * 4);
    int*            row_ptr   = (int*)carve((size_t)(N + 1) * 4);
    int*            hcnt      = (int*)carve((size_t)B * NB * 4);  // bucket-major
    int*            btot      = (int*)carve((size_t)B * 4);
    int*            edge_base = (int*)carve((size_t)(B + 1) * 4);
    unsigned int*   ebuf      = (unsigned int*)carve((size_t)E * 4);
    unsigned short* colidx    = (unsigned short*)carve((size_t)(E + 16) * 2);  // +16 pad
    float*          stats     = (float*)carve(3 * 512 * 4);
    float*          bnAB      = (float*)carve(512 * 4);
    half_t* W1t = (half_t*)carve((size_t)256 * 128 * 2);
    half_t* W2t = (half_t*)carve((size_t)128 * 256 * 2);
    half_t* W3t = (half_t*)carve((size_t)64 * 128 * 2);
    half_t* W4t = (half_t*)carve((size_t)64 * 64 * 2);  // padded to 64 cols
    half_t* hA  = (half_t*)carve((size_t)N * 256 * 2);  // Z1
    half_t* hB  = (half_t*)carve((size_t)N * 128 * 2);  // xh, P2
    half_t* hC  = (half_t*)carve((size_t)N * 128 * 2);  // P1, Z2
    half_t* hD1 = (half_t*)carve((size_t)N * 64 * 2);   // P3
    half_t* hD2 = (half_t*)carve((size_t)N * 64 * 2);   // Z3
    half_t* hE  = (half_t*)carve((size_t)N * 64 * 2);   // P4 padded [N,64]
    (void)n_in; (void)out_size; (void)ws_size;

    // zero colidx pad + stats slots (one memset each per launch; deterministic)
    hipMemsetAsync(colidx + E, 0, 32, stream);
    hipMemsetAsync(stats, 0, 3 * 512 * 4, stream);

    // CSR build (bucketed; all passes parallel)
    csr_hist_kernel<<<NB, 256, 0, stream>>>(ei + E, hcnt, E, B, NB, chunk);
    csr_bscan_kernel<<<B, 256, 0, stream>>>(hcnt, btot, NB);
    csr_ebase_kernel<<<1, 256, 0, stream>>>(btot, edge_base, row_ptr, B, E, N);
    csr_part_kernel<<<NB, 256, 0, stream>>>(ei, hcnt, edge_base, ebuf, E, B, NB, chunk);
    csr_fill_kernel<<<B, 256, 0, stream>>>(ebuf, edge_base, row_ptr, dinv, colidx, N);

    // all weight transposes (fp16) in one launch
    wtall_kernel<<<(77824 + 255) / 256, 256, 0, stream>>>(W1, W2, W3, W4, W1t, W2t, W3t, W4t);

    int nTiles = (N + 63) / 64;
    int gb = nTiles < 512 ? nTiles : 512;  // 2 blocks/CU (64KB LDS each)
    int ab = (N + 3) / 4;                  // agg blocks (4 nodes each)

    // L1: x->fp16, aggregate(128), MFMA GEMM -> Z1 fp16 [N,256]
    f2h_kernel<<<(N * 128 / 4 + 255) / 256, 256, 0, stream>>>(x, hB, N * 128 / 4);
    aggh128_kernel<<<ab, 256, 0, stream>>>(hB, hC, row_ptr, colidx, dinv, N);
    mgemm_kernel<128, 16, false><<<gb, 256, 0, stream>>>(hC, W1t, nullptr, nullptr, hA,
                                                         N, 256, nTiles);
    stats2_kernel<256><<<512, 256, 0, stream>>>(hA, stats, N);
    bnfin_kernel<<<1, 256, 0, stream>>>(stats, g1, be1, bnAB, N, 256);

    // L2: GEMM (BN1+PReLU fused) -> P2 fp16 [N,128], aggregate -> Z2
    mgemm_kernel<256, 8, true><<<gb, 256, 0, stream>>>(hA, W2t, bnAB, pa, hB, N, 128, nTiles);
    aggh128_kernel<<<ab, 256, 0, stream>>>(hB, hC, row_ptr, colidx, dinv, N);
    stats2_kernel<128><<<512, 256, 0, stream>>>(hC, stats + 512, N);
    bnfin_kernel<<<1, 256, 0, stream>>>(stats + 512, g2, be2, bnAB, N, 128);

    // L3: GEMM (BN2 fused) -> P3 [N,64], aggregate -> Z3
    mgemm_kernel<128, 4, true><<<gb, 256, 0, stream>>>(hC, W3t, bnAB, pa, hD1, N, 64, nTiles);
    aggh64_kernel<<<ab, 256, 0, stream>>>(hD1, hD2, row_ptr, colidx, dinv, N);
    stats2_kernel<64><<<512, 256, 0, stream>>>(hD2, stats + 1024, N);
    bnfin_kernel<<<1, 256, 0, stream>>>(stats + 1024, g3, be3, bnAB, N, 64);

    // L4: GEMM (BN3 fused) -> P4 padded [N,64], aggregate + b4 + log_softmax -> out (f32)
    mgemm_kernel<64, 4, true><<<gb, 256, 0, stream>>>(hD2, W4t, bnAB, pa, hE, N, 64, nTiles);
    aggsm64_kernel<<<ab, 256, 0, stream>>>(hE, (float*)d_out, row_ptr, colidx, dinv, b4, N);
}